// Round 7
// baseline (438.598 us; speedup 1.0000x reference)
//
#include <hip/hip_runtime.h>

#define N1 4096
#define N2 2048
#define PD 256
#define DZ 128
#define PD2 258
#define PD2P 264
#define FD 772
#define FDP 776
#define APN 272      // lmFT rows padded; row 258 = ones -> attr_sum
#define APLD 72
#define SPLITS 16

typedef short s8v __attribute__((ext_vector_type(8)));
typedef float f32x4 __attribute__((ext_vector_type(4)));

__device__ __forceinline__ short f2b(float f) {
    union { float f; unsigned u; } v; v.f = f;
    unsigned r = v.u + 0x7fffu + ((v.u >> 16) & 1u);
    return (short)(r >> 16);
}
__device__ __forceinline__ float sb2f(short s) {
    union { unsigned u; float f; } v;
    v.u = ((unsigned)(unsigned short)s) << 16;
    return v.f;
}

struct P {
    const float *lmX, *lmY, *tgX, *lmd, *tgd;
    const float *aqw, *aqb, *akw, *akb, *w1w, *w1b, *w2w, *w2b;
    const float *pqw, *pqb, *pkw, *pkb, *pvw, *pvb;
    const float *g1, *g2, *g3, *al, *be;
    short *lmFTb, *qb, *kk, *q2, *tgp0b, *tgp1b, *finalFb, *w1wb, *w2wb, *pqwb, *E;
    float *appart, *v2b, *part2, *Z;
    float *router0, *routerp0, *router1, *dscore, *rou0, *rou1;
    float *out, *outF;
    unsigned *bar;
};

// manual grid barrier: monotonic counter, device-scope atomics + agent fences.
// 256 blocks == 256 CUs and one block always fits a CU => all co-resident.
__device__ __forceinline__ void gbar(unsigned* cnt, unsigned target) {
    __syncthreads();
    if (threadIdx.x == 0) {
        __threadfence();                 // release: prior writes visible device-wide
        atomicAdd(cnt, 1u);              // device scope by default on gfx950
        while (__hip_atomic_load(cnt, __ATOMIC_RELAXED, __HIP_MEMORY_SCOPE_AGENT) < target)
            __builtin_amdgcn_s_sleep(2);
        __threadfence();                 // acquire: invalidate stale cache lines
    }
    __syncthreads();
}

// flat-prep region sizes
#define F_TGX   (N2 * PD)
#define F_W     (PD2 * PD2P)
#define F_PQ    (DZ * FDP)
#define F_DEL   4096
#define F_Z     2048
#define F_FPAD  (N2 * 4)
#define F_TPAD  (N2 * 6)
#define FT_TOT  (F_TGX + 2 * F_W + F_PQ + F_DEL + F_Z + F_FPAD + F_TPAD)

__device__ __forceinline__ void mfma64(const short* Als, const short* Bls,
                                       f32x4 acc[2][2], int wm, int wn, int lm, int lq) {
    s8v af[2], bf[2];
#pragma unroll
    for (int mt = 0; mt < 2; ++mt)
        af[mt] = *(const s8v*)(Als + (wm * 32 + mt * 16 + lm) * 40 + lq * 8);
#pragma unroll
    for (int nt = 0; nt < 2; ++nt)
        bf[nt] = *(const s8v*)(Bls + (wn * 32 + nt * 16 + lm) * 40 + lq * 8);
#pragma unroll
    for (int mt = 0; mt < 2; ++mt)
#pragma unroll
        for (int nt = 0; nt < 2; ++nt)
            acc[mt][nt] = __builtin_amdgcn_mfma_f32_16x16x32_bf16(
                af[mt], bf[nt], acc[mt][nt], 0, 0, 0);
}

__global__ __launch_bounds__(256) void mega(P p) {
    __shared__ __align__(16) short LDS[28800];   // 57.6 KB
    const int bid = blockIdx.x, tid = threadIdx.x;
    const int wave = tid >> 6, lane = tid & 63;
    const int wm = wave >> 1, wn = wave & 1;
    const int lm = lane & 15, lq = lane >> 4;
    const f32x4 zero4 = {0.f, 0.f, 0.f, 0.f};

    // ================= S0: prep (lmFT tiled transpose + flat copies) =========
    for (int j = bid; j < 320; j += 256) {          // 64 row-tiles x 5 col-tiles
        int rt = j / 5, ct = j - rt * 5;
        int r0 = rt * 64, c0 = ct * 64;
        __syncthreads();
#pragma unroll
        for (int l = 0; l < 16; ++l) {
            int idx = l * 256 + tid;
            int i = idx >> 6, jj = idx & 63;
            int c = c0 + jj;
            float v = 0.f;
            if (c < PD) v = p.lmX[(size_t)(r0 + i) * PD + c];
            else if (c < PD2) v = p.lmY[(size_t)(r0 + i) * 2 + (c - PD)];
            else if (c == PD2) v = 1.f;              // ones col -> attr_sum
            LDS[jj * 65 + i] = f2b(v);
        }
        __syncthreads();
#pragma unroll
        for (int l = 0; l < 16; ++l) {
            int idx = l * 256 + tid;
            int cc = idx >> 6, i = idx & 63;
            if (c0 + cc < APN)
                p.lmFTb[(size_t)(c0 + cc) * N1 + r0 + i] = LDS[cc * 65 + i];
        }
    }
    for (int i0 = bid * 256 + tid; i0 < FT_TOT; i0 += 65536) {
        int j = i0;
        if (j < F_TGX) {
            int r = j >> 8, c = j & 255;
            float v = p.tgX[j];
            p.outF[(size_t)r * FD + c] = v;
            p.finalFb[(size_t)r * FDP + c] = f2b(v);
            continue;
        }
        j -= F_TGX;
        if (j < F_W) { int r = j / PD2P, c = j - r * PD2P;
            p.w1wb[j] = (c < PD2) ? f2b(p.w1w[r * PD2 + c]) : (short)0; continue; }
        j -= F_W;
        if (j < F_W) { int r = j / PD2P, c = j - r * PD2P;
            p.w2wb[j] = (c < PD2) ? f2b(p.w2w[r * PD2 + c]) : (short)0; continue; }
        j -= F_W;
        if (j < F_PQ) { int r = j / FDP, c = j - r * FDP;
            p.pqwb[j] = (c < FD) ? f2b(p.pqw[r * FD + c]) : (short)0; continue; }
        j -= F_PQ;
        if (j < F_DEL) {
            float a = p.al[0], b = p.be[0];
            p.dscore[j] = __expf(-p.g1[0] * (a * p.lmd[j] + b));
            float y0 = p.lmY[2 * j], y1 = p.lmY[2 * j + 1];
            p.v2b[2 * j]     = p.pvw[0] * y0 + p.pvw[1] * y1 + p.pvb[0];
            p.v2b[2 * j + 1] = p.pvw[2] * y0 + p.pvw[3] * y1 + p.pvb[1];
            if (j < N2) {
                float t = a * p.tgd[j] + b;
                p.rou0[j] = __expf(-p.g2[0] * t);
                p.rou1[j] = __expf(-p.g3[0] * t);
            }
            continue;
        }
        j -= F_DEL;
        if (j < F_Z) { p.Z[j] = 0.f; continue; }
        j -= F_Z;
        if (j < F_FPAD) { int r = j >> 2;
            p.finalFb[(size_t)r * FDP + FD + (j & 3)] = 0; continue; }
        j -= F_FPAD;
        { int r = j / 6; p.tgp1b[(size_t)r * PD2P + PD2 + (j - r * 6)] = 0; }
    }
    gbar(p.bar, 256u * 1);

    // ================= S1: router + kk GEMM + qb GEMM ========================
    for (int j = bid; j < 578; j += 256) {
        __syncthreads();
        if (j < 258) {                       // router column j
            float* r1 = (float*)LDS;
            float* r2 = r1 + 256;
            float* r3 = r2 + 256;
            const short* rowp = p.lmFTb + (size_t)j * N1;
            float s1 = 0.f, s2 = 0.f, s3 = 0.f;
            for (int i = tid; i < N1; i += 256) {
                float v = sb2f(rowp[i]);
                float d = p.dscore[i];
                s1 += v; s2 += d * v; s3 += d;
            }
            r1[tid] = s1; r2[tid] = s2; r3[tid] = s3; __syncthreads();
            for (int o = 128; o > 0; o >>= 1) {
                if (tid < o) { r1[tid] += r1[tid + o]; r2[tid] += r2[tid + o]; r3[tid] += r3[tid + o]; }
                __syncthreads();
            }
            if (tid == 0) {
                float r0v = r1[0] / (float)N1;
                p.router0[j] = r0v;
                p.routerp0[j] = (r2[0] + r0v) / (1.f + r3[0] + 1e-12f);
            }
        } else if (j < 514) {                // kk tile: lm_X @ [ak|pk]^T
            int jt = j - 258;
            int row0 = (jt >> 2) * 64, col0 = (jt & 3) * 64;
            short* Als = LDS;
            short* Bls = LDS + 64 * 40;
            f32x4 acc[2][2] = {{zero4, zero4}, {zero4, zero4}};
            int r = tid >> 2, cgp = tid & 3;
            for (int k0 = 0; k0 < 256; k0 += 32) {
                int gk = k0 + cgp * 8;
                const float* ap = p.lmX + (size_t)(row0 + r) * PD + gk;
                int c = col0 + r;
                const float* bp = (c < 128) ? p.akw + (size_t)c * PD + gk
                                            : p.pkw + (size_t)(c - 128) * PD + gk;
                s8v va, vb;
#pragma unroll
                for (int q = 0; q < 8; ++q) { va[q] = f2b(ap[q]); vb[q] = f2b(bp[q]); }
                *(s8v*)(Als + r * 40 + cgp * 8) = va;
                *(s8v*)(Bls + r * 40 + cgp * 8) = vb;
                __syncthreads();
                mfma64(Als, Bls, acc, wm, wn, lm, lq);
                __syncthreads();
            }
#pragma unroll
            for (int mt = 0; mt < 2; ++mt)
#pragma unroll
                for (int nt = 0; nt < 2; ++nt) {
                    int c = col0 + wn * 32 + nt * 16 + lm;
                    float bv = (c < 128) ? p.akb[c] : p.pkb[c - 128];
#pragma unroll
                    for (int i = 0; i < 4; ++i) {
                        int rr = row0 + wm * 32 + mt * 16 + lq * 4 + i;
                        p.kk[(size_t)rr * 256 + c] = f2b(acc[mt][nt][i] + bv);
                    }
                }
        } else {                             // qb tile: tg_X @ aq^T, scaled
            int jt = j - 514;
            int row0 = (jt >> 1) * 64, col0 = (jt & 1) * 64;
            short* Als = LDS;
            short* Bls = LDS + 64 * 40;
            f32x4 acc[2][2] = {{zero4, zero4}, {zero4, zero4}};
            int r = tid >> 2, cgp = tid & 3;
            for (int k0 = 0; k0 < 256; k0 += 32) {
                int gk = k0 + cgp * 8;
                const float* ap = p.tgX + (size_t)(row0 + r) * PD + gk;
                const float* bp = p.aqw + (size_t)(col0 + r) * PD + gk;
                s8v va, vb;
#pragma unroll
                for (int q = 0; q < 8; ++q) { va[q] = f2b(ap[q]); vb[q] = f2b(bp[q]); }
                *(s8v*)(Als + r * 40 + cgp * 8) = va;
                *(s8v*)(Bls + r * 40 + cgp * 8) = vb;
                __syncthreads();
                mfma64(Als, Bls, acc, wm, wn, lm, lq);
                __syncthreads();
            }
            const float INV_TEMP = 0.08838834764831845f;
#pragma unroll
            for (int mt = 0; mt < 2; ++mt)
#pragma unroll
                for (int nt = 0; nt < 2; ++nt) {
                    int c = col0 + wn * 32 + nt * 16 + lm;
                    float bv = p.aqb[c];
#pragma unroll
                    for (int i = 0; i < 4; ++i) {
                        int rr = row0 + wm * 32 + mt * 16 + lq * 4 + i;
                        p.qb[(size_t)rr * DZ + c] = f2b(INV_TEMP * (acc[mt][nt][i] + bv));
                    }
                }
        }
    }
    gbar(p.bar, 256u * 2);

    // ================= S2: E = exp(q.k), Z rowsums; + router1 ================
    for (int j = bid; j < 513; j += 256) {
        __syncthreads();
        if (j < 512) {
            int row0 = (j >> 5) * 128, col0 = (j & 31) * 128;
            short* Als = LDS;
            short* Bls = LDS + 128 * 40;
            f32x4 acc[4][4];
#pragma unroll
            for (int mt = 0; mt < 4; ++mt)
#pragma unroll
                for (int nt = 0; nt < 4; ++nt) acc[mt][nt] = zero4;
            for (int k0 = 0; k0 < 128; k0 += 32) {
#pragma unroll
                for (int l = 0; l < 2; ++l) {
                    int id = l * 256 + tid;
                    int r = id >> 2, cgp = id & 3;
                    int gk = k0 + cgp * 8;
                    *(s8v*)(Als + r * 40 + cgp * 8) =
                        *(const s8v*)(p.qb + (size_t)(row0 + r) * DZ + gk);
                    *(s8v*)(Bls + r * 40 + cgp * 8) =
                        *(const s8v*)(p.kk + (size_t)(col0 + r) * 256 + gk);
                }
                __syncthreads();
                s8v af[4], bf[4];
#pragma unroll
                for (int mt = 0; mt < 4; ++mt)
                    af[mt] = *(const s8v*)(Als + (wm * 64 + mt * 16 + lm) * 40 + lq * 8);
#pragma unroll
                for (int nt = 0; nt < 4; ++nt)
                    bf[nt] = *(const s8v*)(Bls + (wn * 64 + nt * 16 + lm) * 40 + lq * 8);
#pragma unroll
                for (int mt = 0; mt < 4; ++mt)
#pragma unroll
                    for (int nt = 0; nt < 4; ++nt)
                        acc[mt][nt] = __builtin_amdgcn_mfma_f32_16x16x32_bf16(
                            af[mt], bf[nt], acc[mt][nt], 0, 0, 0);
                __syncthreads();
            }
#pragma unroll
            for (int mt = 0; mt < 4; ++mt)
#pragma unroll
                for (int i = 0; i < 4; ++i) {
                    int r = row0 + wm * 64 + mt * 16 + lq * 4 + i;
                    float rs = 0.f;
#pragma unroll
                    for (int nt = 0; nt < 4; ++nt) {
                        int c = col0 + wn * 64 + nt * 16 + lm;
                        float e = __expf(acc[mt][nt][i]);
                        p.E[(size_t)r * N1 + c] = f2b(e);
                        rs += e;
                    }
#pragma unroll
                    for (int msk = 1; msk < 16; msk <<= 1) rs += __shfl_xor(rs, msk, 64);
                    if (lm == 0) atomicAdd(&p.Z[r], rs);
                }
        } else {                              // router1 (single block)
            for (int c = tid; c < PD2; c += 256) {
                float s = p.w1b[c];
                const float* wr = p.w1w + (size_t)c * PD2;
                for (int k = 0; k < PD2; ++k) s += p.routerp0[k] * wr[k];
                p.router1[c] = s;
            }
        }
    }
    gbar(p.bar, 256u * 3);

    // ================= S3: AP split-K GEMM (attr computed in staging) ========
    {
        int s = bid & 15, row0 = (bid >> 4) * 128;
        int kbase = s * (N1 / SPLITS);
        short* Als = LDS;
        short* Bls = LDS + 128 * APLD;
        f32x4 acc0[17], acc1[17];
#pragma unroll
        for (int nt = 0; nt < 17; ++nt) { acc0[nt] = zero4; acc1[nt] = zero4; }
        for (int it = 0; it < (N1 / SPLITS) / 64; ++it) {
            int k0 = kbase + it * 64;
#pragma unroll
            for (int l = 0; l < 4; ++l) {
                int id = l * 256 + tid;
                int r = id >> 3, g = id & 7;
                s8v ev = *(const s8v*)(p.E + (size_t)(row0 + r) * N1 + k0 + g * 8);
                float invZ = __builtin_amdgcn_rcpf(p.Z[row0 + r]);
                s8v av;
#pragma unroll
                for (int q = 0; q < 8; ++q)
                    av[q] = f2b(__expf(sb2f(ev[q]) * invZ));
                *(s8v*)(Als + r * APLD + g * 8) = av;
            }
#pragma unroll
            for (int l = 0; l < 9; ++l) {
                int id = l * 256 + tid;
                if (id < APN * 8) {
                    int r = id >> 3, g = id & 7;
                    *(s8v*)(Bls + r * APLD + g * 8) =
                        *(const s8v*)(p.lmFTb + (size_t)r * N1 + k0 + g * 8);
                }
            }
            __syncthreads();
            s8v a00 = *(const s8v*)(Als + (wave * 32 + lm) * APLD + lq * 8);
            s8v a01 = *(const s8v*)(Als + (wave * 32 + lm) * APLD + 32 + lq * 8);
            s8v a10 = *(const s8v*)(Als + (wave * 32 + 16 + lm) * APLD + lq * 8);
            s8v a11 = *(const s8v*)(Als + (wave * 32 + 16 + lm) * APLD + 32 + lq * 8);
#pragma unroll
            for (int nt = 0; nt < 17; ++nt) {
                s8v b0 = *(const s8v*)(Bls + (nt * 16 + lm) * APLD + lq * 8);
                s8v b1 = *(const s8v*)(Bls + (nt * 16 + lm) * APLD + 32 + lq * 8);
                acc0[nt] = __builtin_amdgcn_mfma_f32_16x16x32_bf16(a00, b0, acc0[nt], 0, 0, 0);
                acc0[nt] = __builtin_amdgcn_mfma_f32_16x16x32_bf16(a01, b1, acc0[nt], 0, 0, 0);
                acc1[nt] = __builtin_amdgcn_mfma_f32_16x16x32_bf16(a10, b0, acc1[nt], 0, 0, 0);
                acc1[nt] = __builtin_amdgcn_mfma_f32_16x16x32_bf16(a11, b1, acc1[nt], 0, 0, 0);
            }
            __syncthreads();
        }
        float* op = p.appart + (size_t)s * N2 * APN;
#pragma unroll
        for (int nt = 0; nt < 17; ++nt) {
            int c = nt * 16 + lm;
#pragma unroll
            for (int i = 0; i < 4; ++i) {
                int r = row0 + wave * 32 + lq * 4 + i;
                op[(size_t)r * APN + c] = acc0[nt][i];
                op[(size_t)(r + 16) * APN + c] = acc1[nt][i];
            }
        }
    }
    gbar(p.bar, 256u * 4);

    // ================= S4: reduce partials -> tgp0 ===========================
    for (int rr = 0; rr < 8; ++rr) {
        int r = bid * 8 + rr;
        float s0 = 0.f, s1 = 0.f;
#pragma unroll
        for (int s = 0; s < SPLITS; ++s)
            s0 += p.appart[((size_t)s * N2 + r) * APN + tid];
        if (tid < 8) {
#pragma unroll
            for (int s = 0; s < SPLITS; ++s)
                s1 += p.appart[((size_t)s * N2 + r) * APN + 256 + tid];
        }
        __syncthreads();
        if (tid == 2) *(float*)LDS = s1;          // col 258 = attr_sum
        __syncthreads();
        float asum = *(float*)LDS;
        float ro = p.rou0[r];
        float inv = 1.f / (1.f + asum + ro + 1e-12f);
        float v = (s0 + p.tgX[(size_t)r * PD + tid] + ro * p.router0[tid]) * inv;
        p.tgp0b[(size_t)r * PD2P + tid] = f2b(v);
        if (tid < 8) {
            int c = 256 + tid;
            float v2 = 0.f;
            if (c < PD2) v2 = (s1 + ro * p.router0[c]) * inv;
            p.tgp0b[(size_t)r * PD2P + c] = f2b(v2);
        }
        __syncthreads();
    }
    gbar(p.bar, 256u * 5);

    // ================= S5/S6: W-layer GEMMs ==================================
    for (int layer = 0; layer < 2; ++layer) {
        const short* A = layer ? p.tgp1b : p.tgp0b;
        const short* B = layer ? p.w2wb : p.w1wb;
        const float* bias = layer ? p.w2b : p.w1b;
        float* oF = p.outF + (layer ? 514 : 256);
        short* oB = p.finalFb + (layer ? 514 : 256);
        for (int j = bid; j < 160; j += 256) {
            int row0 = (j / 5) * 64, col0 = (j % 5) * 64;
            short* Als = LDS;
            short* Bls = LDS + 64 * 40;
            f32x4 acc[2][2] = {{zero4, zero4}, {zero4, zero4}};
            const s8v zero8 = {0, 0, 0, 0, 0, 0, 0, 0};
            int r = tid >> 2, cgp = tid & 3;
            for (int k0 = 0; k0 < PD2P; k0 += 32) {
                int gk = k0 + cgp * 8;
                s8v va = zero8, vb = zero8;
                if (gk < PD2P) {
                    va = *(const s8v*)(A + (size_t)(row0 + r) * PD2P + gk);
                    if (col0 + r < PD2) vb = *(const s8v*)(B + (size_t)(col0 + r) * PD2P + gk);
                }
                *(s8v*)(Als + r * 40 + cgp * 8) = va;
                *(s8v*)(Bls + r * 40 + cgp * 8) = vb;
                __syncthreads();
                mfma64(Als, Bls, acc, wm, wn, lm, lq);
                __syncthreads();
            }
#pragma unroll
            for (int mt = 0; mt < 2; ++mt)
#pragma unroll
                for (int nt = 0; nt < 2; ++nt) {
                    int c = col0 + wn * 32 + nt * 16 + lm;
                    if (c >= PD2) continue;
                    float bv = bias[c];
                    float rc = p.router1[c];
#pragma unroll
                    for (int i = 0; i < 4; ++i) {
                        int rr = row0 + wm * 32 + mt * 16 + lq * 4 + i;
                        float v = acc[mt][nt][i] + bv;
                        oF[(size_t)rr * FD + c] = v;
                        oB[(size_t)rr * FDP + c] = f2b(v);
                        if (layer == 0) {
                            float ro = p.rou1[rr];
                            p.tgp1b[(size_t)rr * PD2P + c] =
                                f2b((v + ro * rc) / (1.f + ro + 1e-12f));
                        }
                    }
                }
        }
        gbar(p.bar, 256u * (6 + layer));
    }

    // ================= S7: q2 = final @ pq^T (K=776) =========================
    for (int j = bid; j < 64; j += 256) {
        int row0 = (j >> 1) * 64, col0 = (j & 1) * 64;
        short* Als = LDS;
        short* Bls = LDS + 64 * 40;
        f32x4 acc[2][2] = {{zero4, zero4}, {zero4, zero4}};
        const s8v zero8 = {0, 0, 0, 0, 0, 0, 0, 0};
        int r = tid >> 2, cgp = tid & 3;
        for (int k0 = 0; k0 < FDP; k0 += 32) {
            int gk = k0 + cgp * 8;
            s8v va = zero8, vb = zero8;
            if (gk < FDP) {
                va = *(const s8v*)(p.finalFb + (size_t)(row0 + r) * FDP + gk);
                vb = *(const s8v*)(p.pqwb + (size_t)(col0 + r) * FDP + gk);
            }
            *(s8v*)(Als + r * 40 + cgp * 8) = va;
            *(s8v*)(Bls + r * 40 + cgp * 8) = vb;
            __syncthreads();
            mfma64(Als, Bls, acc, wm, wn, lm, lq);
            __syncthreads();
        }
        const float INV_TEMP = 0.08838834764831845f;
#pragma unroll
        for (int mt = 0; mt < 2; ++mt)
#pragma unroll
            for (int nt = 0; nt < 2; ++nt) {
                int c = col0 + wn * 32 + nt * 16 + lm;
                float bv = p.pqb[c];
#pragma unroll
                for (int i = 0; i < 4; ++i) {
                    int rr = row0 + wm * 32 + mt * 16 + lq * 4 + i;
                    p.q2[(size_t)rr * DZ + c] = f2b(INV_TEMP * (acc[mt][nt][i] + bv));
                }
            }
    }
    gbar(p.bar, 256u * 8);

    // ================= S8: attention 2 (no-max flash) ========================
    {
        int chunk = bid & 7, row0 = (bid >> 3) * 64;
        short* Qls = LDS;
        short* Kls = LDS + 64 * 136;
        float* Vls = (float*)(LDS + 2 * 64 * 136);
        __syncthreads();
#pragma unroll
        for (int l = 0; l < 4; ++l) {
            int id = l * 256 + tid;
            int r = id >> 4, g = id & 15;
            *(s8v*)(Qls + r * 136 + g * 8) =
                *(const s8v*)(p.q2 + (size_t)(row0 + r) * DZ + g * 8);
        }
        __syncthreads();
        s8v af[4];
#pragma unroll
        for (int ks = 0; ks < 4; ++ks)
            af[ks] = *(const s8v*)(Qls + (wave * 16 + lm) * 136 + ks * 32 + lq * 8);
        float z[4] = {0.f, 0.f, 0.f, 0.f};
        float y0[4] = {0.f, 0.f, 0.f, 0.f};
        float y1[4] = {0.f, 0.f, 0.f, 0.f};
        for (int t = 0; t < 8; ++t) {
            int col0 = chunk * 512 + t * 64;
            __syncthreads();
#pragma unroll
            for (int l = 0; l < 4; ++l) {
                int id = l * 256 + tid;
                int r = id >> 4, g = id & 15;
                *(s8v*)(Kls + r * 136 + g * 8) =
                    *(const s8v*)(p.kk + (size_t)(col0 + r) * 256 + 128 + g * 8);
            }
            if (tid < 128) Vls[tid] = p.v2b[col0 * 2 + tid];
            __syncthreads();
            f32x4 acc[4];
#pragma unroll
            for (int nt = 0; nt < 4; ++nt) acc[nt] = zero4;
#pragma unroll
            for (int nt = 0; nt < 4; ++nt)
#pragma unroll
                for (int ks = 0; ks < 4; ++ks) {
                    s8v bf = *(const s8v*)(Kls + (nt * 16 + lm) * 136 + ks * 32 + lq * 8);
                    acc[nt] = __builtin_amdgcn_mfma_f32_16x16x32_bf16(af[ks], bf, acc[nt], 0, 0, 0);
                }
            float v0[4], v1[4];
#pragma unroll
            for (int nt = 0; nt < 4; ++nt) {
                v0[nt] = Vls[(nt * 16 + lm) * 2];
                v1[nt] = Vls[(nt * 16 + lm) * 2 + 1];
            }
#pragma unroll
            for (int i = 0; i < 4; ++i) {
                float e0 = __expf(acc[0][i]), e1 = __expf(acc[1][i]);
                float e2 = __expf(acc[2][i]), e3 = __expf(acc[3][i]);
                float pz = e0 + e1 + e2 + e3;
                float py0 = e0 * v0[0] + e1 * v0[1] + e2 * v0[2] + e3 * v0[3];
                float py1 = e0 * v1[0] + e1 * v1[1] + e2 * v1[2] + e3 * v1[3];
#pragma unroll
                for (int msk = 1; msk < 16; msk <<= 1) {
                    pz  += __shfl_xor(pz, msk, 64);
                    py0 += __shfl_xor(py0, msk, 64);
                    py1 += __shfl_xor(py1, msk, 64);
                }
                z[i] += pz; y0[i] += py0; y1[i] += py1;
            }
        }
        if (lm == 0) {
#pragma unroll
            for (int i = 0; i < 4; ++i) {
                int r = row0 + wave * 16 + lq * 4 + i;
                float* pp = p.part2 + ((size_t)r * 8 + chunk) * 4;
                pp[0] = z[i]; pp[1] = y0[i]; pp[2] = y1[i];
            }
        }
    }
    gbar(p.bar, 256u * 9);

    // ================= S9: combine ==========================================
    {
        int r = bid * 256 + tid;
        if (r < N2) {
            const float* pp = p.part2 + (size_t)r * 32;
            float Zt = 0.f, Y0 = 0.f, Y1 = 0.f;
#pragma unroll
            for (int c = 0; c < 8; ++c) {
                Zt += pp[c * 4]; Y0 += pp[c * 4 + 1]; Y1 += pp[c * 4 + 2];
            }
            p.out[2 * r] = Y0 / Zt;
            p.out[2 * r + 1] = Y1 / Zt;
        }
    }
}

// ---------------------------------------------------------------- launch
extern "C" void kernel_launch(void* const* d_in, const int* in_sizes, int n_in,
                              void* d_out, int out_size, void* d_ws, size_t ws_size,
                              hipStream_t stream) {
    P prm;
    prm.lmX = (const float*)d_in[0];
    prm.lmY = (const float*)d_in[1];
    prm.tgX = (const float*)d_in[2];
    prm.lmd = (const float*)d_in[4];
    prm.tgd = (const float*)d_in[5];
    prm.aqw = (const float*)d_in[6];
    prm.aqb = (const float*)d_in[7];
    prm.akw = (const float*)d_in[8];
    prm.akb = (const float*)d_in[9];
    prm.w1w = (const float*)d_in[10];
    prm.w1b = (const float*)d_in[11];
    prm.w2w = (const float*)d_in[12];
    prm.w2b = (const float*)d_in[13];
    prm.pqw = (const float*)d_in[14];
    prm.pqb = (const float*)d_in[15];
    prm.pkw = (const float*)d_in[16];
    prm.pkb = (const float*)d_in[17];
    prm.pvw = (const float*)d_in[18];
    prm.pvb = (const float*)d_in[19];
    prm.g1 = (const float*)d_in[20];
    prm.g2 = (const float*)d_in[21];
    prm.g3 = (const float*)d_in[22];
    prm.al = (const float*)d_in[23];
    prm.be = (const float*)d_in[24];

    prm.out = (float*)d_out;
    prm.outF = prm.out + (size_t)N2 * 2;

    char* base = (char*)d_ws;
    size_t off = 0;
    auto allocF = [&](size_t n) -> float* {
        float* q = (float*)(base + off);
        off += (n * 4 + 255) / 256 * 256;
        return q;
    };
    auto allocS = [&](size_t n) -> short* {
        short* q = (short*)(base + off);
        off += (n * 2 + 255) / 256 * 256;
        return q;
    };

    prm.E       = allocS((size_t)N2 * N1);
    prm.appart  = allocF((size_t)SPLITS * N2 * APN);
    prm.lmFTb   = allocS((size_t)APN * N1);
    prm.qb      = allocS((size_t)N2 * DZ);
    prm.kk      = allocS((size_t)N1 * 256);
    prm.q2      = allocS((size_t)N2 * DZ);
    prm.tgp0b   = allocS((size_t)N2 * PD2P);
    prm.tgp1b   = allocS((size_t)N2 * PD2P);
    prm.finalFb = allocS((size_t)N2 * FDP);
    prm.w1wb    = allocS((size_t)PD2 * PD2P);
    prm.w2wb    = allocS((size_t)PD2 * PD2P);
    prm.pqwb    = allocS((size_t)DZ * FDP);
    prm.v2b     = allocF((size_t)N1 * 2);
    prm.part2   = allocF((size_t)N2 * 32);
    prm.Z       = allocF(N2);
    prm.router0 = allocF(PD2);
    prm.routerp0= allocF(PD2);
    prm.router1 = allocF(PD2);
    prm.dscore  = allocF(N1);
    prm.rou0    = allocF(N2);
    prm.rou1    = allocF(N2);
    prm.bar     = (unsigned*)allocF(64);

    hipMemsetAsync(prm.bar, 0, 256, stream);
    hipLaunchKernelGGL(mega, dim3(256), dim3(256), 0, stream, prm);
}

// Round 8
// 421.190 us; speedup vs baseline: 1.0413x; 1.0413x over previous
//
#include <hip/hip_runtime.h>

#define N1 4096
#define N2 2048
#define PD 256
#define DZ 128
#define PD2 258
#define PD2P 264
#define FD 772
#define FDP 776
#define APN 272      // lmFT rows padded; row 258 = ones -> attr_sum
#define APLD 72
#define SPLITS 16

typedef short s8v __attribute__((ext_vector_type(8)));
typedef float f32x4 __attribute__((ext_vector_type(4)));

__device__ __forceinline__ short f2b(float f) {
    union { float f; unsigned u; } v; v.f = f;
    unsigned r = v.u + 0x7fffu + ((v.u >> 16) & 1u);
    return (short)(r >> 16);
}
__device__ __forceinline__ float sb2f(short s) {
    union { unsigned u; float f; } v;
    v.u = ((unsigned)(unsigned short)s) << 16;
    return v.f;
}

struct P {
    const float *lmX, *lmY, *tgX, *lmd, *tgd;
    const float *aqw, *aqb, *akw, *akb, *w1w, *w1b, *w2w, *w2b;
    const float *pqw, *pqb, *pkw, *pkb, *pvw, *pvb;
    const float *g1, *g2, *g3, *al, *be;
    short *lmFTb, *qb, *kk, *q2, *tgp0b, *tgp1b, *finalFb, *w1wb, *w2wb, *pqwb, *E;
    float *appart, *v2b, *part2, *Z;
    float *router0, *routerp0, *router1, *dscore, *rou0, *rou1;
    float *out, *outF;
    unsigned *bar;
};

// manual grid barrier: 256 blocks == 256 CUs, one block always fits => co-resident.
__device__ __forceinline__ void gbar(unsigned* cnt, unsigned target) {
    __syncthreads();
    if (threadIdx.x == 0) {
        __threadfence();
        atomicAdd(cnt, 1u);
        while (__hip_atomic_load(cnt, __ATOMIC_RELAXED, __HIP_MEMORY_SCOPE_AGENT) < target)
            __builtin_amdgcn_s_sleep(2);
        __threadfence();
    }
    __syncthreads();
}

// flat-prep region sizes
#define F_TGX   (N2 * PD)
#define F_W     (PD2 * PD2P)
#define F_PQ    (DZ * FDP)
#define F_DEL   4096
#define F_Z     2048
#define F_FPAD  (N2 * 4)
#define F_TPAD  (N2 * 6)
#define FT_TOT  (F_TGX + 2 * F_W + F_PQ + F_DEL + F_Z + F_FPAD + F_TPAD)

__device__ __forceinline__ void mfma64(const short* Als, const short* Bls,
                                       f32x4 acc[2][2], int wm, int wn, int lm, int lq) {
    s8v af[2], bf[2];
#pragma unroll
    for (int mt = 0; mt < 2; ++mt)
        af[mt] = *(const s8v*)(Als + (wm * 32 + mt * 16 + lm) * 40 + lq * 8);
#pragma unroll
    for (int nt = 0; nt < 2; ++nt)
        bf[nt] = *(const s8v*)(Bls + (wn * 32 + nt * 16 + lm) * 40 + lq * 8);
#pragma unroll
    for (int mt = 0; mt < 2; ++mt)
#pragma unroll
        for (int nt = 0; nt < 2; ++nt)
            acc[mt][nt] = __builtin_amdgcn_mfma_f32_16x16x32_bf16(
                af[mt], bf[nt], acc[mt][nt], 0, 0, 0);
}

// 256 blocks x 512 threads; two 256-thread teams per block for most stages.
__global__ __launch_bounds__(512, 2) void mega(P p) {
    __shared__ __align__(16) short LDS[28800];   // 57.6 KB
    const int tid512 = threadIdx.x;
    const int bid = blockIdx.x;
    const int team = tid512 >> 8;
    const int t = tid512 & 255;
    const int g = bid * 2 + team;                // global team id 0..511
    short* TB = LDS + team * 14400;              // per-team 28.8 KB
    const int lane = tid512 & 63;
    const int wv = t >> 6;                       // wave within team 0..3
    const int w8 = tid512 >> 6;                  // wave within block 0..7
    const int wm = wv >> 1, wn = wv & 1;
    const int lm = lane & 15, lq = lane >> 4;
    const f32x4 zero4 = {0.f, 0.f, 0.f, 0.f};
    const s8v zero8 = {0, 0, 0, 0, 0, 0, 0, 0};

    // ================= S0: prep (lmFT transpose per team + flat copies) ======
    for (int j = g; j < 320; j += 512) {         // 320 even: both teams together
        int rt = j / 5, ct = j - rt * 5;
        int r0 = rt * 64, c0 = ct * 64;
#pragma unroll
        for (int l = 0; l < 16; ++l) {
            int idx = l * 256 + t;
            int i = idx >> 6, jj = idx & 63;
            int c = c0 + jj;
            float v = 0.f;
            if (c < PD) v = p.lmX[(size_t)(r0 + i) * PD + c];
            else if (c < PD2) v = p.lmY[(size_t)(r0 + i) * 2 + (c - PD)];
            else if (c == PD2) v = 1.f;
            TB[jj * 65 + i] = f2b(v);
        }
        __syncthreads();
#pragma unroll
        for (int l = 0; l < 16; ++l) {
            int idx = l * 256 + t;
            int cc = idx >> 6, i = idx & 63;
            if (c0 + cc < APN)
                p.lmFTb[(size_t)(c0 + cc) * N1 + r0 + i] = TB[cc * 65 + i];
        }
    }
    for (int i0 = bid * 512 + tid512; i0 < FT_TOT; i0 += 131072) {
        int j = i0;
        if (j < F_TGX) {
            int r = j >> 8, c = j & 255;
            float v = p.tgX[j];
            p.outF[(size_t)r * FD + c] = v;
            p.finalFb[(size_t)r * FDP + c] = f2b(v);
            continue;
        }
        j -= F_TGX;
        if (j < F_W) { int r = j / PD2P, c = j - r * PD2P;
            p.w1wb[j] = (c < PD2) ? f2b(p.w1w[r * PD2 + c]) : (short)0; continue; }
        j -= F_W;
        if (j < F_W) { int r = j / PD2P, c = j - r * PD2P;
            p.w2wb[j] = (c < PD2) ? f2b(p.w2w[r * PD2 + c]) : (short)0; continue; }
        j -= F_W;
        if (j < F_PQ) { int r = j / FDP, c = j - r * FDP;
            p.pqwb[j] = (c < FD) ? f2b(p.pqw[r * FD + c]) : (short)0; continue; }
        j -= F_PQ;
        if (j < F_DEL) {
            float a = p.al[0], b = p.be[0];
            p.dscore[j] = __expf(-p.g1[0] * (a * p.lmd[j] + b));
            float y0 = p.lmY[2 * j], y1 = p.lmY[2 * j + 1];
            p.v2b[2 * j]     = p.pvw[0] * y0 + p.pvw[1] * y1 + p.pvb[0];
            p.v2b[2 * j + 1] = p.pvw[2] * y0 + p.pvw[3] * y1 + p.pvb[1];
            if (j < N2) {
                float tt = a * p.tgd[j] + b;
                p.rou0[j] = __expf(-p.g2[0] * tt);
                p.rou1[j] = __expf(-p.g3[0] * tt);
            }
            continue;
        }
        j -= F_DEL;
        if (j < F_Z) { p.Z[j] = 0.f; continue; }
        j -= F_Z;
        if (j < F_FPAD) { int r = j >> 2;
            p.finalFb[(size_t)r * FDP + FD + (j & 3)] = 0; continue; }
        j -= F_FPAD;
        { int r = j / 6; p.tgp1b[(size_t)r * PD2P + PD2 + (j - r * 6)] = 0; }
    }
    gbar(p.bar, 256u * 1);

    // ================= S1: router + kk GEMM + qb GEMM (per team) =============
    // type boundaries (258, 514) are even => both teams of a block always
    // take the same branch => __syncthreads counts match.
    for (int j = g; j < 578; j += 512) {
        if (j < 258) {                       // router column j
            float* r1 = (float*)TB;
            float* r2 = r1 + 256;
            float* r3 = r2 + 256;
            const short* rowp = p.lmFTb + (size_t)j * N1;
            float s1 = 0.f, s2 = 0.f, s3 = 0.f;
            for (int i = t; i < N1; i += 256) {
                float v = sb2f(rowp[i]);
                float d = p.dscore[i];
                s1 += v; s2 += d * v; s3 += d;
            }
            r1[t] = s1; r2[t] = s2; r3[t] = s3; __syncthreads();
            for (int o = 128; o > 0; o >>= 1) {
                if (t < o) { r1[t] += r1[t + o]; r2[t] += r2[t + o]; r3[t] += r3[t + o]; }
                __syncthreads();
            }
            if (t == 0) {
                float r0v = r1[0] / (float)N1;
                p.router0[j] = r0v;
                p.routerp0[j] = (r2[0] + r0v) / (1.f + r3[0] + 1e-12f);
            }
        } else if (j < 514) {                // kk tile: lm_X @ [ak|pk]^T
            int jt = j - 258;
            int row0 = (jt >> 2) * 64, col0 = (jt & 3) * 64;
            short* Als = TB;
            short* Bls = TB + 64 * 40;
            f32x4 acc[2][2] = {{zero4, zero4}, {zero4, zero4}};
            int r = t >> 2, cgp = t & 3;
            for (int k0 = 0; k0 < 256; k0 += 32) {
                int gk = k0 + cgp * 8;
                const float* ap = p.lmX + (size_t)(row0 + r) * PD + gk;
                int c = col0 + r;
                const float* bp = (c < 128) ? p.akw + (size_t)c * PD + gk
                                            : p.pkw + (size_t)(c - 128) * PD + gk;
                s8v va, vb;
#pragma unroll
                for (int q = 0; q < 8; ++q) { va[q] = f2b(ap[q]); vb[q] = f2b(bp[q]); }
                *(s8v*)(Als + r * 40 + cgp * 8) = va;
                *(s8v*)(Bls + r * 40 + cgp * 8) = vb;
                __syncthreads();
                mfma64(Als, Bls, acc, wm, wn, lm, lq);
                __syncthreads();
            }
#pragma unroll
            for (int mt = 0; mt < 2; ++mt)
#pragma unroll
                for (int nt = 0; nt < 2; ++nt) {
                    int c = col0 + wn * 32 + nt * 16 + lm;
                    float bv = (c < 128) ? p.akb[c] : p.pkb[c - 128];
#pragma unroll
                    for (int i = 0; i < 4; ++i) {
                        int rr = row0 + wm * 32 + mt * 16 + lq * 4 + i;
                        p.kk[(size_t)rr * 256 + c] = f2b(acc[mt][nt][i] + bv);
                    }
                }
        } else {                             // qb tile: tg_X @ aq^T, scaled
            int jt = j - 514;
            int row0 = (jt >> 1) * 64, col0 = (jt & 1) * 64;
            short* Als = TB;
            short* Bls = TB + 64 * 40;
            f32x4 acc[2][2] = {{zero4, zero4}, {zero4, zero4}};
            int r = t >> 2, cgp = t & 3;
            for (int k0 = 0; k0 < 256; k0 += 32) {
                int gk = k0 + cgp * 8;
                const float* ap = p.tgX + (size_t)(row0 + r) * PD + gk;
                const float* bp = p.aqw + (size_t)(col0 + r) * PD + gk;
                s8v va, vb;
#pragma unroll
                for (int q = 0; q < 8; ++q) { va[q] = f2b(ap[q]); vb[q] = f2b(bp[q]); }
                *(s8v*)(Als + r * 40 + cgp * 8) = va;
                *(s8v*)(Bls + r * 40 + cgp * 8) = vb;
                __syncthreads();
                mfma64(Als, Bls, acc, wm, wn, lm, lq);
                __syncthreads();
            }
            const float INV_TEMP = 0.08838834764831845f;
#pragma unroll
            for (int mt = 0; mt < 2; ++mt)
#pragma unroll
                for (int nt = 0; nt < 2; ++nt) {
                    int c = col0 + wn * 32 + nt * 16 + lm;
                    float bv = p.aqb[c];
#pragma unroll
                    for (int i = 0; i < 4; ++i) {
                        int rr = row0 + wm * 32 + mt * 16 + lq * 4 + i;
                        p.qb[(size_t)rr * DZ + c] = f2b(INV_TEMP * (acc[mt][nt][i] + bv));
                    }
                }
        }
    }
    gbar(p.bar, 256u * 2);

    // ================= S2: E = exp(q.k) per team; + router1 (syncless) =======
    for (int j = g; j < 513; j += 512) {
        if (j < 512) {
            int row0 = (j >> 5) * 128, col0 = (j & 31) * 128;
            short* Als = TB;
            short* Bls = TB + 128 * 40;
            f32x4 acc[4][4];
#pragma unroll
            for (int mt = 0; mt < 4; ++mt)
#pragma unroll
                for (int nt = 0; nt < 4; ++nt) acc[mt][nt] = zero4;
            for (int k0 = 0; k0 < 128; k0 += 32) {
#pragma unroll
                for (int l = 0; l < 2; ++l) {
                    int id = l * 256 + t;
                    int r = id >> 2, cgp = id & 3;
                    int gk = k0 + cgp * 8;
                    *(s8v*)(Als + r * 40 + cgp * 8) =
                        *(const s8v*)(p.qb + (size_t)(row0 + r) * DZ + gk);
                    *(s8v*)(Bls + r * 40 + cgp * 8) =
                        *(const s8v*)(p.kk + (size_t)(col0 + r) * 256 + gk);
                }
                __syncthreads();
                s8v af[4], bf[4];
#pragma unroll
                for (int mt = 0; mt < 4; ++mt)
                    af[mt] = *(const s8v*)(Als + (wm * 64 + mt * 16 + lm) * 40 + lq * 8);
#pragma unroll
                for (int nt = 0; nt < 4; ++nt)
                    bf[nt] = *(const s8v*)(Bls + (wn * 64 + nt * 16 + lm) * 40 + lq * 8);
#pragma unroll
                for (int mt = 0; mt < 4; ++mt)
#pragma unroll
                    for (int nt = 0; nt < 4; ++nt)
                        acc[mt][nt] = __builtin_amdgcn_mfma_f32_16x16x32_bf16(
                            af[mt], bf[nt], acc[mt][nt], 0, 0, 0);
                __syncthreads();
            }
#pragma unroll
            for (int mt = 0; mt < 4; ++mt)
#pragma unroll
                for (int i = 0; i < 4; ++i) {
                    int r = row0 + wm * 64 + mt * 16 + lq * 4 + i;
                    float rs = 0.f;
#pragma unroll
                    for (int nt = 0; nt < 4; ++nt) {
                        int c = col0 + wn * 64 + nt * 16 + lm;
                        float e = __expf(acc[mt][nt][i]);
                        p.E[(size_t)r * N1 + c] = f2b(e);
                        rs += e;
                    }
#pragma unroll
                    for (int msk = 1; msk < 16; msk <<= 1) rs += __shfl_xor(rs, msk, 64);
                    if (lm == 0) atomicAdd(&p.Z[r], rs);
                }
        } else {                              // router1: NO __syncthreads inside
            for (int c = t; c < PD2; c += 256) {
                float s = p.w1b[c];
                const float* wr = p.w1w + (size_t)c * PD2;
                for (int k = 0; k < PD2; ++k) s += p.routerp0[k] * wr[k];
                p.router1[c] = s;
            }
        }
    }
    gbar(p.bar, 256u * 3);

    // ================= S3: AP split-K GEMM (block-wide, 8 waves) =============
    {
        int s = bid & 15, row0 = (bid >> 4) * 128;
        int kbase = s * (N1 / SPLITS);
        short* Als = LDS;                 // 128 x APLD = 9216 shorts
        short* Bls = LDS + 128 * APLD;    // 272 x APLD = 19584 shorts
        f32x4 acc[17];
#pragma unroll
        for (int nt = 0; nt < 17; ++nt) acc[nt] = zero4;
        for (int it = 0; it < (N1 / SPLITS) / 64; ++it) {
            int k0 = kbase + it * 64;
#pragma unroll
            for (int l = 0; l < 2; ++l) {          // A: 128 rows x 8 groups, with exp
                int id = l * 512 + tid512;
                int r = id >> 3, gg = id & 7;
                s8v ev = *(const s8v*)(p.E + (size_t)(row0 + r) * N1 + k0 + gg * 8);
                float invZ = __builtin_amdgcn_rcpf(p.Z[row0 + r]);
                s8v av;
#pragma unroll
                for (int q = 0; q < 8; ++q)
                    av[q] = f2b(__expf(sb2f(ev[q]) * invZ));
                *(s8v*)(Als + r * APLD + gg * 8) = av;
            }
#pragma unroll
            for (int l = 0; l < 5; ++l) {          // B: 272 rows x 8 groups = 2176
                int id = l * 512 + tid512;
                if (id < APN * 8) {
                    int r = id >> 3, gg = id & 7;
                    *(s8v*)(Bls + r * APLD + gg * 8) =
                        *(const s8v*)(p.lmFTb + (size_t)r * N1 + k0 + gg * 8);
                }
            }
            __syncthreads();
            s8v a0 = *(const s8v*)(Als + (w8 * 16 + lm) * APLD + lq * 8);
            s8v a1 = *(const s8v*)(Als + (w8 * 16 + lm) * APLD + 32 + lq * 8);
#pragma unroll
            for (int nt = 0; nt < 17; ++nt) {
                s8v b0 = *(const s8v*)(Bls + (nt * 16 + lm) * APLD + lq * 8);
                s8v b1 = *(const s8v*)(Bls + (nt * 16 + lm) * APLD + 32 + lq * 8);
                acc[nt] = __builtin_amdgcn_mfma_f32_16x16x32_bf16(a0, b0, acc[nt], 0, 0, 0);
                acc[nt] = __builtin_amdgcn_mfma_f32_16x16x32_bf16(a1, b1, acc[nt], 0, 0, 0);
            }
            __syncthreads();
        }
        float* op = p.appart + (size_t)s * N2 * APN;
#pragma unroll
        for (int nt = 0; nt < 17; ++nt) {
            int c = nt * 16 + lm;
#pragma unroll
            for (int i = 0; i < 4; ++i) {
                int r = row0 + w8 * 16 + lq * 4 + i;
                op[(size_t)r * APN + c] = acc[nt][i];
            }
        }
    }
    gbar(p.bar, 256u * 4);

    // ================= S4: reduce partials -> tgp0 (per team, 4 rows) ========
    for (int rr = 0; rr < 4; ++rr) {
        int r = bid * 8 + team * 4 + rr;
        float s0 = 0.f, s1 = 0.f;
#pragma unroll
        for (int s = 0; s < SPLITS; ++s)
            s0 += p.appart[((size_t)s * N2 + r) * APN + t];
        if (t < 8) {
#pragma unroll
            for (int s = 0; s < SPLITS; ++s)
                s1 += p.appart[((size_t)s * N2 + r) * APN + 256 + t];
        }
        __syncthreads();
        if (t == 2) *(float*)TB = s1;          // col 258 = attr_sum
        __syncthreads();
        float asum = *(float*)TB;
        float ro = p.rou0[r];
        float inv = 1.f / (1.f + asum + ro + 1e-12f);
        float v = (s0 + p.tgX[(size_t)r * PD + t] + ro * p.router0[t]) * inv;
        p.tgp0b[(size_t)r * PD2P + t] = f2b(v);
        if (t < 8) {
            int c = 256 + t;
            float v2 = 0.f;
            if (c < PD2) v2 = (s1 + ro * p.router0[c]) * inv;
            p.tgp0b[(size_t)r * PD2P + c] = f2b(v2);
        }
        __syncthreads();
    }
    gbar(p.bar, 256u * 5);

    // ================= S5/S6: W-layer GEMMs (per team) =======================
    for (int layer = 0; layer < 2; ++layer) {
        const short* A = layer ? p.tgp1b : p.tgp0b;
        const short* B = layer ? p.w2wb : p.w1wb;
        const float* bias = layer ? p.w2b : p.w1b;
        float* oF = p.outF + (layer ? 514 : 256);
        short* oB = p.finalFb + (layer ? 514 : 256);
        for (int j = g; j < 160; j += 512) {
            int row0 = (j / 5) * 64, col0 = (j % 5) * 64;
            short* Als = TB;
            short* Bls = TB + 64 * 40;
            f32x4 acc[2][2] = {{zero4, zero4}, {zero4, zero4}};
            int r = t >> 2, cgp = t & 3;
            for (int k0 = 0; k0 < PD2P; k0 += 32) {
                int gk = k0 + cgp * 8;
                s8v va = zero8, vb = zero8;
                if (gk < PD2P) {
                    va = *(const s8v*)(A + (size_t)(row0 + r) * PD2P + gk);
                    if (col0 + r < PD2) vb = *(const s8v*)(B + (size_t)(col0 + r) * PD2P + gk);
                }
                *(s8v*)(Als + r * 40 + cgp * 8) = va;
                *(s8v*)(Bls + r * 40 + cgp * 8) = vb;
                __syncthreads();
                mfma64(Als, Bls, acc, wm, wn, lm, lq);
                __syncthreads();
            }
#pragma unroll
            for (int mt = 0; mt < 2; ++mt)
#pragma unroll
                for (int nt = 0; nt < 2; ++nt) {
                    int c = col0 + wn * 32 + nt * 16 + lm;
                    if (c >= PD2) continue;
                    float bv = bias[c];
                    float rc = p.router1[c];
#pragma unroll
                    for (int i = 0; i < 4; ++i) {
                        int rr = row0 + wm * 32 + mt * 16 + lq * 4 + i;
                        float v = acc[mt][nt][i] + bv;
                        oF[(size_t)rr * FD + c] = v;
                        oB[(size_t)rr * FDP + c] = f2b(v);
                        if (layer == 0) {
                            float ro = p.rou1[rr];
                            p.tgp1b[(size_t)rr * PD2P + c] =
                                f2b((v + ro * rc) / (1.f + ro + 1e-12f));
                        }
                    }
                }
        }
        gbar(p.bar, 256u * (6 + layer));
    }

    // ================= S7: q2 = final @ pq^T (K=776, per team) ===============
    for (int j = g; j < 64; j += 512) {
        int row0 = (j >> 1) * 64, col0 = (j & 1) * 64;
        short* Als = TB;
        short* Bls = TB + 64 * 40;
        f32x4 acc[2][2] = {{zero4, zero4}, {zero4, zero4}};
        int r = t >> 2, cgp = t & 3;
        for (int k0 = 0; k0 < FDP; k0 += 32) {
            int gk = k0 + cgp * 8;
            s8v va = zero8, vb = zero8;
            if (gk < FDP) {
                va = *(const s8v*)(p.finalFb + (size_t)(row0 + r) * FDP + gk);
                vb = *(const s8v*)(p.pqwb + (size_t)(col0 + r) * FDP + gk);
            }
            *(s8v*)(Als + r * 40 + cgp * 8) = va;
            *(s8v*)(Bls + r * 40 + cgp * 8) = vb;
            __syncthreads();
            mfma64(Als, Bls, acc, wm, wn, lm, lq);
            __syncthreads();
        }
        const float INV_TEMP = 0.08838834764831845f;
#pragma unroll
        for (int mt = 0; mt < 2; ++mt)
#pragma unroll
            for (int nt = 0; nt < 2; ++nt) {
                int c = col0 + wn * 32 + nt * 16 + lm;
                float bv = p.pqb[c];
#pragma unroll
                for (int i = 0; i < 4; ++i) {
                    int rr = row0 + wm * 32 + mt * 16 + lq * 4 + i;
                    p.q2[(size_t)rr * DZ + c] = f2b(INV_TEMP * (acc[mt][nt][i] + bv));
                }
            }
    }
    gbar(p.bar, 256u * 8);

    // ================= S8: attention 2 (per team; 16 chunks x 32 rowblocks) ==
    {
        int j = g;                           // 0..511, all active
        int chunk = j & 15, row0 = (j >> 4) * 64;
        short* Qls = TB;                     // 64*136 = 8704 shorts
        float* Vls = (float*)(TB + 8704);    // 128 floats
#pragma unroll
        for (int l = 0; l < 4; ++l) {
            int id = l * 256 + t;
            int r = id >> 4, gg = id & 15;
            *(s8v*)(Qls + r * 136 + gg * 8) =
                *(const s8v*)(p.q2 + (size_t)(row0 + r) * DZ + gg * 8);
        }
        __syncthreads();
        s8v af[4];
#pragma unroll
        for (int ks = 0; ks < 4; ++ks)
            af[ks] = *(const s8v*)(Qls + (wv * 16 + lm) * 136 + ks * 32 + lq * 8);
        float z[4] = {0.f, 0.f, 0.f, 0.f};
        float y0[4] = {0.f, 0.f, 0.f, 0.f};
        float y1[4] = {0.f, 0.f, 0.f, 0.f};
        short* Kls = TB;                     // overlays Q (frags already read)
        for (int tt = 0; tt < 4; ++tt) {
            int col0 = chunk * 256 + tt * 64;
            __syncthreads();                 // protect prior reads (incl. Q frags)
#pragma unroll
            for (int l = 0; l < 4; ++l) {
                int id = l * 256 + t;
                int r = id >> 4, gg = id & 15;
                *(s8v*)(Kls + r * 136 + gg * 8) =
                    *(const s8v*)(p.kk + (size_t)(col0 + r) * 256 + 128 + gg * 8);
            }
            if (t < 128) Vls[t] = p.v2b[col0 * 2 + t];
            __syncthreads();
            f32x4 acc[4];
#pragma unroll
            for (int nt = 0; nt < 4; ++nt) acc[nt] = zero4;
#pragma unroll
            for (int nt = 0; nt < 4; ++nt)
#pragma unroll
                for (int ks = 0; ks < 4; ++ks) {
                    s8v bf = *(const s8v*)(Kls + (nt * 16 + lm) * 136 + ks * 32 + lq * 8);
                    acc[nt] = __builtin_amdgcn_mfma_f32_16x16x32_bf16(af[ks], bf, acc[nt], 0, 0, 0);
                }
            float v0[4], v1[4];
#pragma unroll
            for (int nt = 0; nt < 4; ++nt) {
                v0[nt] = Vls[(nt * 16 + lm) * 2];
                v1[nt] = Vls[(nt * 16 + lm) * 2 + 1];
            }
#pragma unroll
            for (int i = 0; i < 4; ++i) {
                float e0 = __expf(acc[0][i]), e1 = __expf(acc[1][i]);
                float e2 = __expf(acc[2][i]), e3 = __expf(acc[3][i]);
                float pz = e0 + e1 + e2 + e3;
                float py0 = e0 * v0[0] + e1 * v0[1] + e2 * v0[2] + e3 * v0[3];
                float py1 = e0 * v1[0] + e1 * v1[1] + e2 * v1[2] + e3 * v1[3];
#pragma unroll
                for (int msk = 1; msk < 16; msk <<= 1) {
                    pz  += __shfl_xor(pz, msk, 64);
                    py0 += __shfl_xor(py0, msk, 64);
                    py1 += __shfl_xor(py1, msk, 64);
                }
                z[i] += pz; y0[i] += py0; y1[i] += py1;
            }
        }
        if (lm == 0) {
#pragma unroll
            for (int i = 0; i < 4; ++i) {
                int r = row0 + wv * 16 + lq * 4 + i;
                float* pp = p.part2 + (size_t)r * 64 + chunk * 4;
                pp[0] = z[i]; pp[1] = y0[i]; pp[2] = y1[i];
            }
        }
    }
    gbar(p.bar, 256u * 9);

    // ================= S9: combine ==========================================
    {
        int r = bid * 512 + tid512;
        if (r < N2) {
            const float* pp = p.part2 + (size_t)r * 64;
            float Zt = 0.f, Y0 = 0.f, Y1 = 0.f;
#pragma unroll
            for (int c = 0; c < 16; ++c) {
                Zt += pp[c * 4]; Y0 += pp[c * 4 + 1]; Y1 += pp[c * 4 + 2];
            }
            p.out[2 * r] = Y0 / Zt;
            p.out[2 * r + 1] = Y1 / Zt;
        }
    }
}

// ---------------------------------------------------------------- launch
extern "C" void kernel_launch(void* const* d_in, const int* in_sizes, int n_in,
                              void* d_out, int out_size, void* d_ws, size_t ws_size,
                              hipStream_t stream) {
    P prm;
    prm.lmX = (const float*)d_in[0];
    prm.lmY = (const float*)d_in[1];
    prm.tgX = (const float*)d_in[2];
    prm.lmd = (const float*)d_in[4];
    prm.tgd = (const float*)d_in[5];
    prm.aqw = (const float*)d_in[6];
    prm.aqb = (const float*)d_in[7];
    prm.akw = (const float*)d_in[8];
    prm.akb = (const float*)d_in[9];
    prm.w1w = (const float*)d_in[10];
    prm.w1b = (const float*)d_in[11];
    prm.w2w = (const float*)d_in[12];
    prm.w2b = (const float*)d_in[13];
    prm.pqw = (const float*)d_in[14];
    prm.pqb = (const float*)d_in[15];
    prm.pkw = (const float*)d_in[16];
    prm.pkb = (const float*)d_in[17];
    prm.pvw = (const float*)d_in[18];
    prm.pvb = (const float*)d_in[19];
    prm.g1 = (const float*)d_in[20];
    prm.g2 = (const float*)d_in[21];
    prm.g3 = (const float*)d_in[22];
    prm.al = (const float*)d_in[23];
    prm.be = (const float*)d_in[24];

    prm.out = (float*)d_out;
    prm.outF = prm.out + (size_t)N2 * 2;

    char* base = (char*)d_ws;
    size_t off = 0;
    auto allocF = [&](size_t n) -> float* {
        float* q = (float*)(base + off);
        off += (n * 4 + 255) / 256 * 256;
        return q;
    };
    auto allocS = [&](size_t n) -> short* {
        short* q = (short*)(base + off);
        off += (n * 2 + 255) / 256 * 256;
        return q;
    };

    prm.E       = allocS((size_t)N2 * N1);
    prm.appart  = allocF((size_t)SPLITS * N2 * APN);
    prm.lmFTb   = allocS((size_t)APN * N1);
    prm.qb      = allocS((size_t)N2 * DZ);
    prm.kk      = allocS((size_t)N1 * 256);
    prm.q2      = allocS((size_t)N2 * DZ);
    prm.tgp0b   = allocS((size_t)N2 * PD2P);
    prm.tgp1b   = allocS((size_t)N2 * PD2P);
    prm.finalFb = allocS((size_t)N2 * FDP);
    prm.w1wb    = allocS((size_t)PD2 * PD2P);
    prm.w2wb    = allocS((size_t)PD2 * PD2P);
    prm.pqwb    = allocS((size_t)DZ * FDP);
    prm.v2b     = allocF((size_t)N1 * 2);
    prm.part2   = allocF((size_t)N2 * 64);
    prm.Z       = allocF(N2);
    prm.router0 = allocF(PD2);
    prm.routerp0= allocF(PD2);
    prm.router1 = allocF(PD2);
    prm.dscore  = allocF(N1);
    prm.rou0    = allocF(N2);
    prm.rou1    = allocF(N2);
    prm.bar     = (unsigned*)allocF(64);

    hipMemsetAsync(prm.bar, 0, 256, stream);
    hipLaunchKernelGGL(mega, dim3(256), dim3(512), 0, stream, prm);
}

// Round 9
// 253.479 us; speedup vs baseline: 1.7303x; 1.6616x over previous
//
#include <hip/hip_runtime.h>

#define N1 4096
#define N2 2048
#define PD 256
#define DZ 128
#define PD2 258
#define PD2P 264
#define FD 772
#define FDP 776
#define APN 272      // lmFT rows padded; row 258 = ones -> attr_sum
#define APLD 72
#define SPLITS 16

typedef short s8v __attribute__((ext_vector_type(8)));
typedef float f32x4 __attribute__((ext_vector_type(4)));

__device__ __forceinline__ short f2b(float f) {
    union { float f; unsigned u; } v; v.f = f;
    unsigned r = v.u + 0x7fffu + ((v.u >> 16) & 1u);
    return (short)(r >> 16);
}
__device__ __forceinline__ float sb2f(short s) {
    union { unsigned u; float f; } v;
    v.u = ((unsigned)(unsigned short)s) << 16;
    return v.f;
}

// ---------------------------------------------------------------- cvt_all
// regions: tgX->out cols | w1wb | w2wb | pqwb | lmFTb | delay/v2 | Z | pads
constexpr int R0 = N2 * PD;
constexpr int R1 = R0 + PD2 * PD2P;
constexpr int R2 = R1 + PD2 * PD2P;
constexpr int R3 = R2 + DZ * FDP;
constexpr int R4 = R3 + APN * N1;
constexpr int R5 = R4 + 4096;
constexpr int R6 = R5 + 2048;
constexpr int R7 = R6 + N2 * 4;
constexpr int R8 = R7 + N2 * 6;

__global__ __launch_bounds__(256) void cvt_all(
    const float* __restrict__ lmX, const float* __restrict__ lmY,
    const float* __restrict__ tgX,
    const float* __restrict__ pqw, const float* __restrict__ w1w,
    const float* __restrict__ w2w,
    const float* __restrict__ lmd, const float* __restrict__ tgd,
    const float* __restrict__ g1, const float* __restrict__ g2,
    const float* __restrict__ g3, const float* __restrict__ al,
    const float* __restrict__ be,
    const float* __restrict__ pvw, const float* __restrict__ pvb,
    short* __restrict__ w1wb, short* __restrict__ w2wb,
    short* __restrict__ pqwb, short* __restrict__ lmFTb,
    float* __restrict__ dscore, float* __restrict__ rou0,
    float* __restrict__ rou1, float* __restrict__ v2b,
    float* __restrict__ Z, short* __restrict__ finalFb,
    short* __restrict__ tgp1b, float* __restrict__ outF)
{
    int i = blockIdx.x * 256 + threadIdx.x;
    if (i < R0) { int r = i >> 8, c = i & 255;
                  float v = tgX[i];
                  outF[(size_t)r * FD + c] = v;
                  finalFb[(size_t)r * FDP + c] = f2b(v); return; }
    if (i < R1) { int j = i - R0; int r = j / PD2P, c = j - r * PD2P;
                  w1wb[j] = (c < PD2) ? f2b(w1w[r * PD2 + c]) : (short)0; return; }
    if (i < R2) { int j = i - R1; int r = j / PD2P, c = j - r * PD2P;
                  w2wb[j] = (c < PD2) ? f2b(w2w[r * PD2 + c]) : (short)0; return; }
    if (i < R3) { int j = i - R2; int r = j / FDP, c = j - r * FDP;
                  pqwb[j] = (c < FD) ? f2b(pqw[r * FD + c]) : (short)0; return; }
    if (i < R4) { int j = i - R3; int c = j >> 12, r = j & (N1 - 1);
                  float v = 0.f;
                  if (c < PD) v = lmX[(size_t)r * PD + c];
                  else if (c < PD2) v = lmY[r * 2 + (c - PD)];
                  else if (c == PD2) v = 1.0f;         // ones col -> attr_sum
                  lmFTb[j] = f2b(v); return; }
    if (i < R5) { int j = i - R4;   // j in [0,4096)
                  float a = al[0], b = be[0];
                  dscore[j] = __expf(-g1[0] * (a * lmd[j] + b));
                  float y0 = lmY[2 * j], y1 = lmY[2 * j + 1];
                  v2b[2 * j]     = pvw[0] * y0 + pvw[1] * y1 + pvb[0];
                  v2b[2 * j + 1] = pvw[2] * y0 + pvw[3] * y1 + pvb[1];
                  if (j < N2) { float t = a * tgd[j] + b;
                                rou0[j] = __expf(-g2[0] * t);
                                rou1[j] = __expf(-g3[0] * t); }
                  return; }
    if (i < R6) { Z[i - R5] = 0.f; return; }
    if (i < R7) { int j = i - R6; int r = j >> 2;
                  finalFb[(size_t)r * FDP + FD + (j & 3)] = 0; return; }
    if (i < R8) { int j = i - R7; int r = j / 6;
                  tgp1b[(size_t)r * PD2P + PD2 + (j - r * 6)] = 0; return; }
}

// ---------------------------------------------------------------- router + kk + qb
// blocks 0..257: router col; 258..513: kk 64x64 tile; 514..577: qb tile
__global__ __launch_bounds__(256) void rkq_kernel(
    const float* __restrict__ lmX, const float* __restrict__ tgX,
    const float* __restrict__ aqw, const float* __restrict__ aqb,
    const float* __restrict__ akw, const float* __restrict__ akb,
    const float* __restrict__ pkw, const float* __restrict__ pkb,
    const short* __restrict__ lmFTb, const float* __restrict__ dscore,
    float* __restrict__ router0, float* __restrict__ routerp0,
    short* __restrict__ kk, short* __restrict__ qb)
{
    __shared__ __align__(16) short LDS[5120];      // 10.2 KB
    const int j = blockIdx.x, tid = threadIdx.x;
    const int lane = tid & 63, wv = tid >> 6;
    const int wm = wv >> 1, wn = wv & 1;
    const int lm = lane & 15, lq = lane >> 4;
    const f32x4 zero4 = {0.f, 0.f, 0.f, 0.f};

    if (j < 258) {                                 // router column
        float* r1 = (float*)LDS;
        float* r2 = r1 + 256;
        float* r3 = r2 + 256;
        const short* rowp = lmFTb + (size_t)j * N1;
        float s1 = 0.f, s2 = 0.f, s3 = 0.f;
        for (int i = tid; i < N1; i += 256) {
            float v = sb2f(rowp[i]);
            float d = dscore[i];
            s1 += v; s2 += d * v; s3 += d;
        }
        r1[tid] = s1; r2[tid] = s2; r3[tid] = s3; __syncthreads();
        for (int o = 128; o > 0; o >>= 1) {
            if (tid < o) { r1[tid] += r1[tid + o]; r2[tid] += r2[tid + o]; r3[tid] += r3[tid + o]; }
            __syncthreads();
        }
        if (tid == 0) {
            float r0v = r1[0] / (float)N1;
            router0[j] = r0v;
            routerp0[j] = (r2[0] + r0v) / (1.f + r3[0] + 1e-12f);
        }
        return;
    }
    short* Als = LDS;
    short* Bls = LDS + 64 * 40;
    f32x4 acc[2][2] = {{zero4, zero4}, {zero4, zero4}};
    const int r = tid >> 2, cgp = tid & 3;
    if (j < 514) {                                 // kk tile
        int jt = j - 258;
        int row0 = (jt >> 2) * 64, col0 = (jt & 3) * 64;
        for (int k0 = 0; k0 < 256; k0 += 32) {
            int gk = k0 + cgp * 8;
            const float* ap = lmX + (size_t)(row0 + r) * PD + gk;
            int c = col0 + r;
            const float* bp = (c < 128) ? akw + (size_t)c * PD + gk
                                        : pkw + (size_t)(c - 128) * PD + gk;
            s8v va, vb;
#pragma unroll
            for (int q = 0; q < 8; ++q) { va[q] = f2b(ap[q]); vb[q] = f2b(bp[q]); }
            *(s8v*)(Als + r * 40 + cgp * 8) = va;
            *(s8v*)(Bls + r * 40 + cgp * 8) = vb;
            __syncthreads();
            s8v af[2], bf[2];
#pragma unroll
            for (int mt = 0; mt < 2; ++mt)
                af[mt] = *(const s8v*)(Als + (wm * 32 + mt * 16 + lm) * 40 + lq * 8);
#pragma unroll
            for (int nt = 0; nt < 2; ++nt)
                bf[nt] = *(const s8v*)(Bls + (wn * 32 + nt * 16 + lm) * 40 + lq * 8);
#pragma unroll
            for (int mt = 0; mt < 2; ++mt)
#pragma unroll
                for (int nt = 0; nt < 2; ++nt)
                    acc[mt][nt] = __builtin_amdgcn_mfma_f32_16x16x32_bf16(
                        af[mt], bf[nt], acc[mt][nt], 0, 0, 0);
            __syncthreads();
        }
#pragma unroll
        for (int mt = 0; mt < 2; ++mt)
#pragma unroll
            for (int nt = 0; nt < 2; ++nt) {
                int c = col0 + wn * 32 + nt * 16 + lm;
                float bv = (c < 128) ? akb[c] : pkb[c - 128];
#pragma unroll
                for (int i = 0; i < 4; ++i) {
                    int rr = row0 + wm * 32 + mt * 16 + lq * 4 + i;
                    kk[(size_t)rr * 256 + c] = f2b(acc[mt][nt][i] + bv);
                }
            }
    } else {                                       // qb tile
        int jt = j - 514;
        int row0 = (jt >> 1) * 64, col0 = (jt & 1) * 64;
        for (int k0 = 0; k0 < 256; k0 += 32) {
            int gk = k0 + cgp * 8;
            const float* ap = tgX + (size_t)(row0 + r) * PD + gk;
            const float* bp = aqw + (size_t)(col0 + r) * PD + gk;
            s8v va, vb;
#pragma unroll
            for (int q = 0; q < 8; ++q) { va[q] = f2b(ap[q]); vb[q] = f2b(bp[q]); }
            *(s8v*)(Als + r * 40 + cgp * 8) = va;
            *(s8v*)(Bls + r * 40 + cgp * 8) = vb;
            __syncthreads();
            s8v af[2], bf[2];
#pragma unroll
            for (int mt = 0; mt < 2; ++mt)
                af[mt] = *(const s8v*)(Als + (wm * 32 + mt * 16 + lm) * 40 + lq * 8);
#pragma unroll
            for (int nt = 0; nt < 2; ++nt)
                bf[nt] = *(const s8v*)(Bls + (wn * 32 + nt * 16 + lm) * 40 + lq * 8);
#pragma unroll
            for (int mt = 0; mt < 2; ++mt)
#pragma unroll
                for (int nt = 0; nt < 2; ++nt)
                    acc[mt][nt] = __builtin_amdgcn_mfma_f32_16x16x32_bf16(
                        af[mt], bf[nt], acc[mt][nt], 0, 0, 0);
            __syncthreads();
        }
        const float INV_TEMP = 0.08838834764831845f;
#pragma unroll
        for (int mt = 0; mt < 2; ++mt)
#pragma unroll
            for (int nt = 0; nt < 2; ++nt) {
                int c = col0 + wn * 32 + nt * 16 + lm;
                float bv = aqb[c];
#pragma unroll
                for (int i = 0; i < 4; ++i) {
                    int rr = row0 + wm * 32 + mt * 16 + lq * 4 + i;
                    qb[(size_t)rr * DZ + c] = f2b(INV_TEMP * (acc[mt][nt][i] + bv));
                }
            }
    }
}

// ---------------------------------------------------------------- scores1 + exp (+router1)
__global__ __launch_bounds__(256) void scores_e(
    const short* __restrict__ Q, const short* __restrict__ Kk,
    short* __restrict__ E, float* __restrict__ Z,
    const float* __restrict__ rp0, const float* __restrict__ w1w,
    const float* __restrict__ w1b, float* __restrict__ router1)
{
    const int j = blockIdx.x, tid = threadIdx.x;
    if (j == 512) {                                // router1
        for (int c = tid; c < PD2; c += 256) {
            float s = w1b[c];
            const float* wr = w1w + (size_t)c * PD2;
            for (int k = 0; k < PD2; ++k) s += rp0[k] * wr[k];
            router1[c] = s;
        }
        return;
    }
    __shared__ __align__(16) short LDS[10240];     // 2 x 128 x 40
    short* Als = LDS;
    short* Bls = LDS + 128 * 40;
    const int lane = tid & 63, wv = tid >> 6;
    const int wm = wv >> 1, wn = wv & 1;
    const int lm = lane & 15, lq = lane >> 4;
    const int row0 = (j >> 5) * 128, col0 = (j & 31) * 128;
    const f32x4 zero4 = {0.f, 0.f, 0.f, 0.f};
    f32x4 acc[4][4];
#pragma unroll
    for (int mt = 0; mt < 4; ++mt)
#pragma unroll
        for (int nt = 0; nt < 4; ++nt) acc[mt][nt] = zero4;
    for (int k0 = 0; k0 < 128; k0 += 32) {
#pragma unroll
        for (int l = 0; l < 2; ++l) {
            int id = l * 256 + tid;
            int r = id >> 2, cgp = id & 3;
            int gk = k0 + cgp * 8;
            *(s8v*)(Als + r * 40 + cgp * 8) = *(const s8v*)(Q + (size_t)(row0 + r) * DZ + gk);
            *(s8v*)(Bls + r * 40 + cgp * 8) = *(const s8v*)(Kk + (size_t)(col0 + r) * 256 + gk);
        }
        __syncthreads();
        s8v af[4], bf[4];
#pragma unroll
        for (int mt = 0; mt < 4; ++mt)
            af[mt] = *(const s8v*)(Als + (wm * 64 + mt * 16 + lm) * 40 + lq * 8);
#pragma unroll
        for (int nt = 0; nt < 4; ++nt)
            bf[nt] = *(const s8v*)(Bls + (wn * 64 + nt * 16 + lm) * 40 + lq * 8);
#pragma unroll
        for (int mt = 0; mt < 4; ++mt)
#pragma unroll
            for (int nt = 0; nt < 4; ++nt)
                acc[mt][nt] = __builtin_amdgcn_mfma_f32_16x16x32_bf16(
                    af[mt], bf[nt], acc[mt][nt], 0, 0, 0);
        __syncthreads();
    }
#pragma unroll
    for (int mt = 0; mt < 4; ++mt)
#pragma unroll
        for (int i = 0; i < 4; ++i) {
            int r = row0 + wm * 64 + mt * 16 + lq * 4 + i;
            float rs = 0.f;
#pragma unroll
            for (int nt = 0; nt < 4; ++nt) {
                int c = col0 + wn * 64 + nt * 16 + lm;
                float e = __expf(acc[mt][nt][i]);
                E[(size_t)r * N1 + c] = f2b(e);
                rs += e;
            }
#pragma unroll
            for (int msk = 1; msk < 16; msk <<= 1) rs += __shfl_xor(rs, msk, 64);
            if (lm == 0) atomicAdd(&Z[r], rs);
        }
}

// ---------------------------------------------------------------- AP split-K (512 thr, bf16 partials)
__global__ __launch_bounds__(512) void ap_gemm(const short* __restrict__ E,
                                               const float* __restrict__ Z,
                                               const short* __restrict__ lmFTb,
                                               short* __restrict__ part)
{
    __shared__ __align__(16) short LDS[28800];     // 57.6 KB
    const int tid = threadIdx.x, bid = blockIdx.x;
    const int lane = tid & 63, w8 = tid >> 6;
    const int lm = lane & 15, lq = lane >> 4;
    const int s = bid & 15, row0 = (bid >> 4) * 128;
    const int kbase = s * (N1 / SPLITS);
    short* Als = LDS;
    short* Bls = LDS + 128 * APLD;
    const f32x4 zero4 = {0.f, 0.f, 0.f, 0.f};
    f32x4 acc[17];
#pragma unroll
    for (int nt = 0; nt < 17; ++nt) acc[nt] = zero4;
    for (int it = 0; it < (N1 / SPLITS) / 64; ++it) {
        int k0 = kbase + it * 64;
#pragma unroll
        for (int l = 0; l < 2; ++l) {
            int id = l * 512 + tid;
            int r = id >> 3, gg = id & 7;
            s8v ev = *(const s8v*)(E + (size_t)(row0 + r) * N1 + k0 + gg * 8);
            float invZ = __builtin_amdgcn_rcpf(Z[row0 + r]);
            s8v av;
#pragma unroll
            for (int q = 0; q < 8; ++q)
                av[q] = f2b(__expf(sb2f(ev[q]) * invZ));
            *(s8v*)(Als + r * APLD + gg * 8) = av;
        }
#pragma unroll
        for (int l = 0; l < 5; ++l) {
            int id = l * 512 + tid;
            if (id < APN * 8) {
                int r = id >> 3, gg = id & 7;
                *(s8v*)(Bls + r * APLD + gg * 8) =
                    *(const s8v*)(lmFTb + (size_t)r * N1 + k0 + gg * 8);
            }
        }
        __syncthreads();
        s8v a0 = *(const s8v*)(Als + (w8 * 16 + lm) * APLD + lq * 8);
        s8v a1 = *(const s8v*)(Als + (w8 * 16 + lm) * APLD + 32 + lq * 8);
#pragma unroll
        for (int nt = 0; nt < 17; ++nt) {
            s8v b0 = *(const s8v*)(Bls + (nt * 16 + lm) * APLD + lq * 8);
            s8v b1 = *(const s8v*)(Bls + (nt * 16 + lm) * APLD + 32 + lq * 8);
            acc[nt] = __builtin_amdgcn_mfma_f32_16x16x32_bf16(a0, b0, acc[nt], 0, 0, 0);
            acc[nt] = __builtin_amdgcn_mfma_f32_16x16x32_bf16(a1, b1, acc[nt], 0, 0, 0);
        }
        __syncthreads();
    }
    short* op = part + (size_t)s * N2 * APN;
#pragma unroll
    for (int nt = 0; nt < 17; ++nt) {
        int c = nt * 16 + lm;
#pragma unroll
        for (int i = 0; i < 4; ++i) {
            int r = row0 + w8 * 16 + lq * 4 + i;
            op[(size_t)r * APN + c] = f2b(acc[nt][i]);
        }
    }
}

// ---------------------------------------------------------------- tgp0 reduce+fixup
__global__ __launch_bounds__(256) void fix_tgp0(const short* __restrict__ part,
                                                const float* __restrict__ tgX,
                                                const float* __restrict__ rou0,
                                                const float* __restrict__ router0,
                                                short* __restrict__ outb) {
    int r = blockIdx.x;
    int tid = threadIdx.x;
    __shared__ float sAsum;
    float s0 = 0.f, s1 = 0.f;
#pragma unroll
    for (int s = 0; s < SPLITS; ++s)
        s0 += sb2f(part[((size_t)s * N2 + r) * APN + tid]);
    if (tid < 8) {
#pragma unroll
        for (int s = 0; s < SPLITS; ++s)
            s1 += sb2f(part[((size_t)s * N2 + r) * APN + 256 + tid]);
    }
    if (tid == 2) sAsum = s1;   // col 258
    __syncthreads();
    float ro = rou0[r];
    float inv = 1.f / (1.f + sAsum + ro + 1e-12f);
    {
        float v = (s0 + tgX[(size_t)r * PD + tid] + ro * router0[tid]) * inv;
        outb[(size_t)r * PD2P + tid] = f2b(v);
    }
    if (tid < 8) {
        int c = 256 + tid;
        float v = 0.f;
        if (c < PD2) v = (s1 + ro * router0[c]) * inv;
        outb[(size_t)r * PD2P + c] = f2b(v);
    }
}

// ---------------------------------------------------------------- W-layer GEMM
__global__ __launch_bounds__(256) void w_gemm(
    const short* __restrict__ A, const short* __restrict__ B,
    const float* __restrict__ bias,
    float* __restrict__ outFcol, short* __restrict__ fFbcol,
    const float* __restrict__ rou1, const float* __restrict__ router1,
    short* __restrict__ tgp1b)
{
    __shared__ __align__(16) short LDS[5120];
    short* Als = LDS;
    short* Bls = LDS + 64 * 40;
    const int tid = threadIdx.x;
    const int lane = tid & 63, wv = tid >> 6;
    const int wm = wv >> 1, wn = wv & 1;
    const int lm = lane & 15, lq = lane >> 4;
    const int row0 = blockIdx.y * 64, col0 = blockIdx.x * 64;
    const f32x4 zero4 = {0.f, 0.f, 0.f, 0.f};
    f32x4 acc[2][2] = {{zero4, zero4}, {zero4, zero4}};
    const s8v zero8 = {0, 0, 0, 0, 0, 0, 0, 0};
    const int r = tid >> 2, cgp = tid & 3;
    for (int k0 = 0; k0 < PD2P; k0 += 32) {
        int gk = k0 + cgp * 8;
        s8v va = zero8, vb = zero8;
        if (gk < PD2P) {
            va = *(const s8v*)(A + (size_t)(row0 + r) * PD2P + gk);
            if (col0 + r < PD2) vb = *(const s8v*)(B + (size_t)(col0 + r) * PD2P + gk);
        }
        *(s8v*)(Als + r * 40 + cgp * 8) = va;
        *(s8v*)(Bls + r * 40 + cgp * 8) = vb;
        __syncthreads();
        s8v af[2], bf[2];
#pragma unroll
        for (int mt = 0; mt < 2; ++mt)
            af[mt] = *(const s8v*)(Als + (wm * 32 + mt * 16 + lm) * 40 + lq * 8);
#pragma unroll
        for (int nt = 0; nt < 2; ++nt)
            bf[nt] = *(const s8v*)(Bls + (wn * 32 + nt * 16 + lm) * 40 + lq * 8);
#pragma unroll
        for (int mt = 0; mt < 2; ++mt)
#pragma unroll
            for (int nt = 0; nt < 2; ++nt)
                acc[mt][nt] = __builtin_amdgcn_mfma_f32_16x16x32_bf16(
                    af[mt], bf[nt], acc[mt][nt], 0, 0, 0);
        __syncthreads();
    }
#pragma unroll
    for (int mt = 0; mt < 2; ++mt)
#pragma unroll
        for (int nt = 0; nt < 2; ++nt) {
            int c = col0 + wn * 32 + nt * 16 + lm;
            if (c >= PD2) continue;
            float bv = bias[c];
            float rc = router1 ? router1[c] : 0.f;
#pragma unroll
            for (int i = 0; i < 4; ++i) {
                int rr = row0 + wm * 32 + mt * 16 + lq * 4 + i;
                float v = acc[mt][nt][i] + bv;
                outFcol[(size_t)rr * FD + c] = v;
                fFbcol[(size_t)rr * FDP + c] = f2b(v);
                if (tgp1b) {
                    float ro = rou1[rr];
                    tgp1b[(size_t)rr * PD2P + c] =
                        f2b((v + ro * rc) / (1.f + ro + 1e-12f));
                }
            }
        }
}

// ---------------------------------------------------------------- q2 projection (K=776)
__global__ __launch_bounds__(256) void q2_gemm(
    const short* __restrict__ A, const short* __restrict__ B,
    const float* __restrict__ bias, short* __restrict__ outB)
{
    __shared__ __align__(16) short LDS[5120];
    short* Als = LDS;
    short* Bls = LDS + 64 * 40;
    const int tid = threadIdx.x;
    const int lane = tid & 63, wv = tid >> 6;
    const int wm = wv >> 1, wn = wv & 1;
    const int lm = lane & 15, lq = lane >> 4;
    const int row0 = blockIdx.y * 64, col0 = blockIdx.x * 64;
    const f32x4 zero4 = {0.f, 0.f, 0.f, 0.f};
    f32x4 acc[2][2] = {{zero4, zero4}, {zero4, zero4}};
    const s8v zero8 = {0, 0, 0, 0, 0, 0, 0, 0};
    const int r = tid >> 2, cgp = tid & 3;
    for (int k0 = 0; k0 < FDP; k0 += 32) {
        int gk = k0 + cgp * 8;
        s8v va = zero8, vb = zero8;
        if (gk < FDP) {
            va = *(const s8v*)(A + (size_t)(row0 + r) * FDP + gk);
            vb = *(const s8v*)(B + (size_t)(col0 + r) * FDP + gk);
        }
        *(s8v*)(Als + r * 40 + cgp * 8) = va;
        *(s8v*)(Bls + r * 40 + cgp * 8) = vb;
        __syncthreads();
        s8v af[2], bf[2];
#pragma unroll
        for (int mt = 0; mt < 2; ++mt)
            af[mt] = *(const s8v*)(Als + (wm * 32 + mt * 16 + lm) * 40 + lq * 8);
#pragma unroll
        for (int nt = 0; nt < 2; ++nt)
            bf[nt] = *(const s8v*)(Bls + (wn * 32 + nt * 16 + lm) * 40 + lq * 8);
#pragma unroll
        for (int mt = 0; mt < 2; ++mt)
#pragma unroll
            for (int nt = 0; nt < 2; ++nt)
                acc[mt][nt] = __builtin_amdgcn_mfma_f32_16x16x32_bf16(
                    af[mt], bf[nt], acc[mt][nt], 0, 0, 0);
        __syncthreads();
    }
    const float INV_TEMP = 0.08838834764831845f;
#pragma unroll
    for (int mt = 0; mt < 2; ++mt)
#pragma unroll
        for (int nt = 0; nt < 2; ++nt) {
            int c = col0 + wn * 32 + nt * 16 + lm;
            float bv = bias[c];
#pragma unroll
            for (int i = 0; i < 4; ++i) {
                int rr = row0 + wm * 32 + mt * 16 + lq * 4 + i;
                outB[(size_t)rr * DZ + c] = f2b(INV_TEMP * (acc[mt][nt][i] + bv));
            }
        }
}

// ---------------------------------------------------------------- attention 2 + last-block combine
__global__ __launch_bounds__(256) void attn2_flash(
    const short* __restrict__ Q, const short* __restrict__ Kk,
    const float* __restrict__ V, float* __restrict__ part2,
    unsigned* __restrict__ done, float* __restrict__ out)
{
    __shared__ __align__(16) short Qls[64 * 136];
    __shared__ __align__(16) short Kls[64 * 136];
    __shared__ float Vls[128];
    __shared__ unsigned sdone;
    const int tid = threadIdx.x;
    const int lane = tid & 63, wv = tid >> 6;
    const int lm = lane & 15, lq = lane >> 4;
    const int chunk = blockIdx.x & 7, row0 = (blockIdx.x >> 3) * 64;
    const f32x4 zero4 = {0.f, 0.f, 0.f, 0.f};
#pragma unroll
    for (int l = 0; l < 4; ++l) {
        int id = l * 256 + tid;
        int r = id >> 4, g = id & 15;
        *(s8v*)(Qls + r * 136 + g * 8) = *(const s8v*)(Q + (size_t)(row0 + r) * DZ + g * 8);
    }
    __syncthreads();
    s8v af[4];
#pragma unroll
    for (int ks = 0; ks < 4; ++ks)
        af[ks] = *(const s8v*)(Qls + (wv * 16 + lm) * 136 + ks * 32 + lq * 8);
    float z[4] = {0.f, 0.f, 0.f, 0.f};
    float y0[4] = {0.f, 0.f, 0.f, 0.f};
    float y1[4] = {0.f, 0.f, 0.f, 0.f};
    for (int t = 0; t < 8; ++t) {
        int col0 = chunk * 512 + t * 64;
        __syncthreads();
#pragma unroll
        for (int l = 0; l < 4; ++l) {
            int id = l * 256 + tid;
            int r = id >> 4, g = id & 15;
            *(s8v*)(Kls + r * 136 + g * 8) =
                *(const s8v*)(Kk + (size_t)(col0 + r) * 256 + 128 + g * 8);
        }
        if (tid < 128) Vls[tid] = V[col0 * 2 + tid];
        __syncthreads();
        f32x4 acc[4];
#pragma unroll
        for (int nt = 0; nt < 4; ++nt) acc[nt] = zero4;
#pragma unroll
        for (int nt = 0; nt < 4; ++nt)
#pragma unroll
            for (int ks = 0; ks < 4; ++ks) {
                s8v bf = *(const s8v*)(Kls + (nt * 16 + lm) * 136 + ks * 32 + lq * 8);
                acc[nt] = __builtin_amdgcn_mfma_f32_16x16x32_bf16(af[ks], bf, acc[nt], 0, 0, 0);
            }
        float v0[4], v1[4];
#pragma unroll
        for (int nt = 0; nt < 4; ++nt) {
            v0[nt] = Vls[(nt * 16 + lm) * 2];
            v1[nt] = Vls[(nt * 16 + lm) * 2 + 1];
        }
#pragma unroll
        for (int i = 0; i < 4; ++i) {
            float e0 = __expf(acc[0][i]), e1 = __expf(acc[1][i]);
            float e2 = __expf(acc[2][i]), e3 = __expf(acc[3][i]);
            float pz = e0 + e1 + e2 + e3;
            float py0 = e0 * v0[0] + e1 * v0[1] + e2 * v0[2] + e3 * v0[3];
            float py1 = e0 * v1[0] + e1 * v1[1] + e2 * v1[2] + e3 * v1[3];
#pragma unroll
            for (int msk = 1; msk < 16; msk <<= 1) {
                pz  += __shfl_xor(pz, msk, 64);
                py0 += __shfl_xor(py0, msk, 64);
                py1 += __shfl_xor(py1, msk, 64);
            }
            z[i] += pz; y0[i] += py0; y1[i] += py1;
        }
    }
    if (lm == 0) {
#pragma unroll
        for (int i = 0; i < 4; ++i) {
            int r = row0 + wv * 16 + lq * 4 + i;
            float* pp = part2 + ((size_t)r * 8 + chunk) * 4;
            pp[0] = z[i]; pp[1] = y0[i]; pp[2] = y1[i];
        }
    }
    // last-block-done combine
    __threadfence();
    __syncthreads();
    if (tid == 0) sdone = atomicAdd(done, 1u);
    __syncthreads();
    if (sdone == 255u) {
        __threadfence();
        for (int r = tid; r < N2; r += 256) {
            const float* pp = part2 + (size_t)r * 32;
            float Zt = 0.f, Y0 = 0.f, Y1 = 0.f;
#pragma unroll
            for (int c = 0; c < 8; ++c) {
                Zt += pp[c * 4]; Y0 += pp[c * 4 + 1]; Y1 += pp[c * 4 + 2];
            }
            out[2 * r] = Y0 / Zt;
            out[2 * r + 1] = Y1 / Zt;
        }
    }
}

// ---------------------------------------------------------------- launch
extern "C" void kernel_launch(void* const* d_in, const int* in_sizes, int n_in,
                              void* d_out, int out_size, void* d_ws, size_t ws_size,
                              hipStream_t stream) {
    const float* lm_X = (const float*)d_in[0];
    const float* lm_Y = (const float*)d_in[1];
    const float* tg_X = (const float*)d_in[2];
    const float* lm_delay = (const float*)d_in[4];
    const float* tg_delay = (const float*)d_in[5];
    const float* aq_w = (const float*)d_in[6];
    const float* aq_b = (const float*)d_in[7];
    const float* ak_w = (const float*)d_in[8];
    const float* ak_b = (const float*)d_in[9];
    const float* w1_w = (const float*)d_in[10];
    const float* w1_b = (const float*)d_in[11];
    const float* w2_w = (const float*)d_in[12];
    const float* w2_b = (const float*)d_in[13];
    const float* pq_w = (const float*)d_in[14];
    const float* pq_b = (const float*)d_in[15];
    const float* pk_w = (const float*)d_in[16];
    const float* pk_b = (const float*)d_in[17];
    const float* pv_w = (const float*)d_in[18];
    const float* pv_b = (const float*)d_in[19];
    const float* g1 = (const float*)d_in[20];
    const float* g2 = (const float*)d_in[21];
    const float* g3 = (const float*)d_in[22];
    const float* al = (const float*)d_in[23];
    const float* be = (const float*)d_in[24];

    float* out = (float*)d_out;
    float* outF = out + (size_t)N2 * 2;

    char* base = (char*)d_ws;
    size_t off = 0;
    auto allocF = [&](size_t n) -> float* {
        float* q = (float*)(base + off);
        off += (n * 4 + 255) / 256 * 256;
        return q;
    };
    auto allocS = [&](size_t n) -> short* {
        short* q = (short*)(base + off);
        off += (n * 2 + 255) / 256 * 256;
        return q;
    };

    short* E        = allocS((size_t)N2 * N1);
    short* appart   = allocS((size_t)SPLITS * N2 * APN);
    short* lmFTb    = allocS((size_t)APN * N1);
    short* qb       = allocS((size_t)N2 * DZ);
    short* kk       = allocS((size_t)N1 * 256);
    short* q2       = allocS((size_t)N2 * DZ);
    short* tgp0b    = allocS((size_t)N2 * PD2P);
    short* tgp1b    = allocS((size_t)N2 * PD2P);
    short* finalFb  = allocS((size_t)N2 * FDP);
    short* w1wb     = allocS((size_t)PD2 * PD2P);
    short* w2wb     = allocS((size_t)PD2 * PD2P);
    short* pqwb     = allocS((size_t)DZ * FDP);
    float* v2b      = allocF((size_t)N1 * 2);
    float* part2    = allocF((size_t)N2 * 32);
    float* Zbuf     = allocF(N2);
    float* router0  = allocF(PD2);
    float* routerp0 = allocF(PD2);
    float* router1  = allocF(PD2);
    float* dscore   = allocF(N1);
    float* rou0     = allocF(N2);
    float* rou1     = allocF(N2);
    unsigned* done  = (unsigned*)allocF(64);

    hipMemsetAsync(done, 0, 256, stream);

    // 1. conversions / copies / zero-fills
    hipLaunchKernelGGL(cvt_all, dim3((R8 + 255) / 256), dim3(256), 0, stream,
                       lm_X, lm_Y, tg_X, pq_w, w1_w, w2_w,
                       lm_delay, tg_delay, g1, g2, g3, al, be, pv_w, pv_b,
                       w1wb, w2wb, pqwb, lmFTb,
                       dscore, rou0, rou1, v2b, Zbuf, finalFb, tgp1b, outF);
    // 2. router + kk + qb (one kernel, 578 blocks)
    hipLaunchKernelGGL(rkq_kernel, dim3(578), dim3(256), 0, stream,
                       lm_X, tg_X, aq_w, aq_b, ak_w, ak_b, pk_w, pk_b,
                       lmFTb, dscore, router0, routerp0, kk, qb);
    // 3. E = exp(scores), Z rowsums (+router1 block)
    hipLaunchKernelGGL(scores_e, dim3(513), dim3(256), 0, stream,
                       qb, kk, E, Zbuf, routerp0, w1_w, w1_b, router1);
    // 4. AP partials (bf16)
    hipLaunchKernelGGL(ap_gemm, dim3(256), dim3(512), 0, stream, E, Zbuf, lmFTb, appart);
    // 5. tgp0
    hipLaunchKernelGGL(fix_tgp0, dim3(N2), dim3(256), 0, stream,
                       appart, tg_X, rou0, router0, tgp0b);
    // 6. tf1 (+ fused tgp1)
    hipLaunchKernelGGL(w_gemm, dim3(5, 32), dim3(256), 0, stream,
                       tgp0b, w1wb, w1_b, outF + 256, finalFb + 256, rou1, router1, tgp1b);
    // 7. tf2
    hipLaunchKernelGGL(w_gemm, dim3(5, 32), dim3(256), 0, stream,
                       tgp1b, w2wb, w2_b, outF + 514, finalFb + 514,
                       nullptr, nullptr, nullptr);
    // 8. q2
    hipLaunchKernelGGL(q2_gemm, dim3(2, 32), dim3(256), 0, stream,
                       finalFb, pqwb, pq_b, q2);
    // 9. attention 2 + combine
    hipLaunchKernelGGL(attn2_flash, dim3(256), dim3(256), 0, stream,
                       q2, kk, v2b, part2, done, out);
}

// Round 10
// 217.639 us; speedup vs baseline: 2.0153x; 1.1647x over previous
//
#include <hip/hip_runtime.h>

#define N1 4096
#define N2 2048
#define PD 256
#define DZ 128
#define PD2 258
#define PD2P 264
#define FD 772
#define FDP 776
#define APN 272      // lmFT rows padded; row 258 = ones -> attr_sum
#define APLD 72
#define SPLITS 16

typedef short s8v __attribute__((ext_vector_type(8)));
typedef float f32x4 __attribute__((ext_vector_type(4)));

__device__ __forceinline__ short f2b(float f) {
    union { float f; unsigned u; } v; v.f = f;
    unsigned r = v.u + 0x7fffu + ((v.u >> 16) & 1u);
    return (short)(r >> 16);
}
__device__ __forceinline__ float sb2f(short s) {
    union { unsigned u; float f; } v;
    v.u = ((unsigned)(unsigned short)s) << 16;
    return v.f;
}

// ---------------------------------------------------------------- cvt_all
constexpr int R0 = N2 * PD;
constexpr int R1 = R0 + PD2 * PD2P;
constexpr int R2 = R1 + PD2 * PD2P;
constexpr int R3 = R2 + DZ * FDP;
constexpr int R4 = R3 + APN * N1;
constexpr int R5 = R4 + 4096;
constexpr int R6 = R5 + 2048;
constexpr int R7 = R6 + N2 * 4;
constexpr int R8 = R7 + N2 * 6;

__global__ __launch_bounds__(256) void cvt_all(
    const float* __restrict__ lmX, const float* __restrict__ lmY,
    const float* __restrict__ tgX,
    const float* __restrict__ pqw, const float* __restrict__ w1w,
    const float* __restrict__ w2w,
    const float* __restrict__ lmd, const float* __restrict__ tgd,
    const float* __restrict__ g1, const float* __restrict__ g2,
    const float* __restrict__ g3, const float* __restrict__ al,
    const float* __restrict__ be,
    const float* __restrict__ pvw, const float* __restrict__ pvb,
    short* __restrict__ w1wb, short* __restrict__ w2wb,
    short* __restrict__ pqwb, short* __restrict__ lmFTb,
    float* __restrict__ dscore, float* __restrict__ rou0,
    float* __restrict__ rou1, float* __restrict__ v2b,
    float* __restrict__ Z, short* __restrict__ finalFb,
    short* __restrict__ tgp1b, float* __restrict__ outF)
{
    int i = blockIdx.x * 256 + threadIdx.x;
    if (i < R0) { int r = i >> 8, c = i & 255;
                  float v = tgX[i];
                  outF[(size_t)r * FD + c] = v;
                  finalFb[(size_t)r * FDP + c] = f2b(v); return; }
    if (i < R1) { int j = i - R0; int r = j / PD2P, c = j - r * PD2P;
                  w1wb[j] = (c < PD2) ? f2b(w1w[r * PD2 + c]) : (short)0; return; }
    if (i < R2) { int j = i - R1; int r = j / PD2P, c = j - r * PD2P;
                  w2wb[j] = (c < PD2) ? f2b(w2w[r * PD2 + c]) : (short)0; return; }
    if (i < R3) { int j = i - R2; int r = j / FDP, c = j - r * FDP;
                  pqwb[j] = (c < FD) ? f2b(pqw[r * FD + c]) : (short)0; return; }
    if (i < R4) { int j = i - R3; int c = j >> 12, r = j & (N1 - 1);
                  float v = 0.f;
                  if (c < PD) v = lmX[(size_t)r * PD + c];
                  else if (c < PD2) v = lmY[r * 2 + (c - PD)];
                  else if (c == PD2) v = 1.0f;         // ones col -> attr_sum
                  lmFTb[j] = f2b(v); return; }
    if (i < R5) { int j = i - R4;   // j in [0,4096)
                  float a = al[0], b = be[0];
                  dscore[j] = __expf(-g1[0] * (a * lmd[j] + b));
                  float y0 = lmY[2 * j], y1 = lmY[2 * j + 1];
                  v2b[2 * j]     = pvw[0] * y0 + pvw[1] * y1 + pvb[0];
                  v2b[2 * j + 1] = pvw[2] * y0 + pvw[3] * y1 + pvb[1];
                  if (j < N2) { float t = a * tgd[j] + b;
                                rou0[j] = __expf(-g2[0] * t);
                                rou1[j] = __expf(-g3[0] * t); }
                  return; }
    if (i < R6) { Z[i - R5] = 0.f; return; }
    if (i < R7) { int j = i - R6; int r = j >> 2;
                  finalFb[(size_t)r * FDP + FD + (j & 3)] = 0; return; }
    if (i < R8) { int j = i - R7; int r = j / 6;
                  tgp1b[(size_t)r * PD2P + PD2 + (j - r * 6)] = 0; return; }
}

// ---------------------------------------------------------------- router + kk + qb
__global__ __launch_bounds__(256) void rkq_kernel(
    const float* __restrict__ lmX, const float* __restrict__ tgX,
    const float* __restrict__ aqw, const float* __restrict__ aqb,
    const float* __restrict__ akw, const float* __restrict__ akb,
    const float* __restrict__ pkw, const float* __restrict__ pkb,
    const short* __restrict__ lmFTb, const float* __restrict__ dscore,
    float* __restrict__ router0, float* __restrict__ routerp0,
    short* __restrict__ kk, short* __restrict__ qb)
{
    __shared__ __align__(16) short LDS[5120];      // 10.2 KB
    const int j = blockIdx.x, tid = threadIdx.x;
    const int lane = tid & 63, wv = tid >> 6;
    const int wm = wv >> 1, wn = wv & 1;
    const int lm = lane & 15, lq = lane >> 4;
    const f32x4 zero4 = {0.f, 0.f, 0.f, 0.f};

    if (j < 258) {                                 // router column
        float* r1 = (float*)LDS;
        float* r2 = r1 + 256;
        float* r3 = r2 + 256;
        const short* rowp = lmFTb + (size_t)j * N1;
        float s1 = 0.f, s2 = 0.f, s3 = 0.f;
        for (int i = tid; i < N1; i += 256) {
            float v = sb2f(rowp[i]);
            float d = dscore[i];
            s1 += v; s2 += d * v; s3 += d;
        }
        r1[tid] = s1; r2[tid] = s2; r3[tid] = s3; __syncthreads();
        for (int o = 128; o > 0; o >>= 1) {
            if (tid < o) { r1[tid] += r1[tid + o]; r2[tid] += r2[tid + o]; r3[tid] += r3[tid + o]; }
            __syncthreads();
        }
        if (tid == 0) {
            float r0v = r1[0] / (float)N1;
            router0[j] = r0v;
            routerp0[j] = (r2[0] + r0v) / (1.f + r3[0] + 1e-12f);
        }
        return;
    }
    short* Als = LDS;
    short* Bls = LDS + 64 * 40;
    f32x4 acc[2][2] = {{zero4, zero4}, {zero4, zero4}};
    const int r = tid >> 2, cgp = tid & 3;
    if (j < 514) {                                 // kk tile
        int jt = j - 258;
        int row0 = (jt >> 2) * 64, col0 = (jt & 3) * 64;
        for (int k0 = 0; k0 < 256; k0 += 32) {
            int gk = k0 + cgp * 8;
            const float* ap = lmX + (size_t)(row0 + r) * PD + gk;
            int c = col0 + r;
            const float* bp = (c < 128) ? akw + (size_t)c * PD + gk
                                        : pkw + (size_t)(c - 128) * PD + gk;
            s8v va, vb;
#pragma unroll
            for (int q = 0; q < 8; ++q) { va[q] = f2b(ap[q]); vb[q] = f2b(bp[q]); }
            *(s8v*)(Als + r * 40 + cgp * 8) = va;
            *(s8v*)(Bls + r * 40 + cgp * 8) = vb;
            __syncthreads();
            s8v af[2], bf[2];
#pragma unroll
            for (int mt = 0; mt < 2; ++mt)
                af[mt] = *(const s8v*)(Als + (wm * 32 + mt * 16 + lm) * 40 + lq * 8);
#pragma unroll
            for (int nt = 0; nt < 2; ++nt)
                bf[nt] = *(const s8v*)(Bls + (wn * 32 + nt * 16 + lm) * 40 + lq * 8);
#pragma unroll
            for (int mt = 0; mt < 2; ++mt)
#pragma unroll
                for (int nt = 0; nt < 2; ++nt)
                    acc[mt][nt] = __builtin_amdgcn_mfma_f32_16x16x32_bf16(
                        af[mt], bf[nt], acc[mt][nt], 0, 0, 0);
            __syncthreads();
        }
#pragma unroll
        for (int mt = 0; mt < 2; ++mt)
#pragma unroll
            for (int nt = 0; nt < 2; ++nt) {
                int c = col0 + wn * 32 + nt * 16 + lm;
                float bv = (c < 128) ? akb[c] : pkb[c - 128];
#pragma unroll
                for (int i = 0; i < 4; ++i) {
                    int rr = row0 + wm * 32 + mt * 16 + lq * 4 + i;
                    kk[(size_t)rr * 256 + c] = f2b(acc[mt][nt][i] + bv);
                }
            }
    } else {                                       // qb tile
        int jt = j - 514;
        int row0 = (jt >> 1) * 64, col0 = (jt & 1) * 64;
        for (int k0 = 0; k0 < 256; k0 += 32) {
            int gk = k0 + cgp * 8;
            const float* ap = tgX + (size_t)(row0 + r) * PD + gk;
            const float* bp = aqw + (size_t)(col0 + r) * PD + gk;
            s8v va, vb;
#pragma unroll
            for (int q = 0; q < 8; ++q) { va[q] = f2b(ap[q]); vb[q] = f2b(bp[q]); }
            *(s8v*)(Als + r * 40 + cgp * 8) = va;
            *(s8v*)(Bls + r * 40 + cgp * 8) = vb;
            __syncthreads();
            s8v af[2], bf[2];
#pragma unroll
            for (int mt = 0; mt < 2; ++mt)
                af[mt] = *(const s8v*)(Als + (wm * 32 + mt * 16 + lm) * 40 + lq * 8);
#pragma unroll
            for (int nt = 0; nt < 2; ++nt)
                bf[nt] = *(const s8v*)(Bls + (wn * 32 + nt * 16 + lm) * 40 + lq * 8);
#pragma unroll
            for (int mt = 0; mt < 2; ++mt)
#pragma unroll
                for (int nt = 0; nt < 2; ++nt)
                    acc[mt][nt] = __builtin_amdgcn_mfma_f32_16x16x32_bf16(
                        af[mt], bf[nt], acc[mt][nt], 0, 0, 0);
            __syncthreads();
        }
        const float INV_TEMP = 0.08838834764831845f;
#pragma unroll
        for (int mt = 0; mt < 2; ++mt)
#pragma unroll
            for (int nt = 0; nt < 2; ++nt) {
                int c = col0 + wn * 32 + nt * 16 + lm;
                float bv = aqb[c];
#pragma unroll
                for (int i = 0; i < 4; ++i) {
                    int rr = row0 + wm * 32 + mt * 16 + lq * 4 + i;
                    qb[(size_t)rr * DZ + c] = f2b(INV_TEMP * (acc[mt][nt][i] + bv));
                }
            }
    }
}

// ---------------------------------------------------------------- scores1 + exp (+router1)
__global__ __launch_bounds__(256) void scores_e(
    const short* __restrict__ Q, const short* __restrict__ Kk,
    short* __restrict__ E, float* __restrict__ Z,
    const float* __restrict__ rp0, const float* __restrict__ w1w,
    const float* __restrict__ w1b, float* __restrict__ router1)
{
    const int j = blockIdx.x, tid = threadIdx.x;
    if (j == 512) {                                // router1
        for (int c = tid; c < PD2; c += 256) {
            float s = w1b[c];
            const float* wr = w1w + (size_t)c * PD2;
            for (int k = 0; k < PD2; ++k) s += rp0[k] * wr[k];
            router1[c] = s;
        }
        return;
    }
    __shared__ __align__(16) short LDS[10240];     // 2 x 128 x 40
    short* Als = LDS;
    short* Bls = LDS + 128 * 40;
    const int lane = tid & 63, wv = tid >> 6;
    const int wm = wv >> 1, wn = wv & 1;
    const int lm = lane & 15, lq = lane >> 4;
    const int row0 = (j >> 5) * 128, col0 = (j & 31) * 128;
    const f32x4 zero4 = {0.f, 0.f, 0.f, 0.f};
    f32x4 acc[4][4];
#pragma unroll
    for (int mt = 0; mt < 4; ++mt)
#pragma unroll
        for (int nt = 0; nt < 4; ++nt) acc[mt][nt] = zero4;
    for (int k0 = 0; k0 < 128; k0 += 32) {
#pragma unroll
        for (int l = 0; l < 2; ++l) {
            int id = l * 256 + tid;
            int r = id >> 2, cgp = id & 3;
            int gk = k0 + cgp * 8;
            *(s8v*)(Als + r * 40 + cgp * 8) = *(const s8v*)(Q + (size_t)(row0 + r) * DZ + gk);
            *(s8v*)(Bls + r * 40 + cgp * 8) = *(const s8v*)(Kk + (size_t)(col0 + r) * 256 + gk);
        }
        __syncthreads();
        s8v af[4], bf[4];
#pragma unroll
        for (int mt = 0; mt < 4; ++mt)
            af[mt] = *(const s8v*)(Als + (wm * 64 + mt * 16 + lm) * 40 + lq * 8);
#pragma unroll
        for (int nt = 0; nt < 4; ++nt)
            bf[nt] = *(const s8v*)(Bls + (wn * 64 + nt * 16 + lm) * 40 + lq * 8);
#pragma unroll
        for (int mt = 0; mt < 4; ++mt)
#pragma unroll
            for (int nt = 0; nt < 4; ++nt)
                acc[mt][nt] = __builtin_amdgcn_mfma_f32_16x16x32_bf16(
                    af[mt], bf[nt], acc[mt][nt], 0, 0, 0);
        __syncthreads();
    }
#pragma unroll
    for (int mt = 0; mt < 4; ++mt)
#pragma unroll
        for (int i = 0; i < 4; ++i) {
            int r = row0 + wm * 64 + mt * 16 + lq * 4 + i;
            float rs = 0.f;
#pragma unroll
            for (int nt = 0; nt < 4; ++nt) {
                int c = col0 + wn * 64 + nt * 16 + lm;
                float e = __expf(acc[mt][nt][i]);
                E[(size_t)r * N1 + c] = f2b(e);
                rs += e;
            }
#pragma unroll
            for (int msk = 1; msk < 16; msk <<= 1) rs += __shfl_xor(rs, msk, 64);
            if (lm == 0) atomicAdd(&Z[r], rs);
        }
}

// ---------------------------------------------------------------- AP split-K (512 thr, bf16 partials)
__global__ __launch_bounds__(512) void ap_gemm(const short* __restrict__ E,
                                               const float* __restrict__ Z,
                                               const short* __restrict__ lmFTb,
                                               short* __restrict__ part)
{
    __shared__ __align__(16) short LDS[28800];     // 57.6 KB
    const int tid = threadIdx.x, bid = blockIdx.x;
    const int lane = tid & 63, w8 = tid >> 6;
    const int lm = lane & 15, lq = lane >> 4;
    const int s = bid & 15, row0 = (bid >> 4) * 128;
    const int kbase = s * (N1 / SPLITS);
    short* Als = LDS;
    short* Bls = LDS + 128 * APLD;
    const f32x4 zero4 = {0.f, 0.f, 0.f, 0.f};
    f32x4 acc[17];
#pragma unroll
    for (int nt = 0; nt < 17; ++nt) acc[nt] = zero4;
    for (int it = 0; it < (N1 / SPLITS) / 64; ++it) {
        int k0 = kbase + it * 64;
#pragma unroll
        for (int l = 0; l < 2; ++l) {
            int id = l * 512 + tid;
            int r = id >> 3, gg = id & 7;
            s8v ev = *(const s8v*)(E + (size_t)(row0 + r) * N1 + k0 + gg * 8);
            float invZ = __builtin_amdgcn_rcpf(Z[row0 + r]);
            s8v av;
#pragma unroll
            for (int q = 0; q < 8; ++q)
                av[q] = f2b(__expf(sb2f(ev[q]) * invZ));
            *(s8v*)(Als + r * APLD + gg * 8) = av;
        }
#pragma unroll
        for (int l = 0; l < 5; ++l) {
            int id = l * 512 + tid;
            if (id < APN * 8) {
                int r = id >> 3, gg = id & 7;
                *(s8v*)(Bls + r * APLD + gg * 8) =
                    *(const s8v*)(lmFTb + (size_t)r * N1 + k0 + gg * 8);
            }
        }
        __syncthreads();
        s8v a0 = *(const s8v*)(Als + (w8 * 16 + lm) * APLD + lq * 8);
        s8v a1 = *(const s8v*)(Als + (w8 * 16 + lm) * APLD + 32 + lq * 8);
#pragma unroll
        for (int nt = 0; nt < 17; ++nt) {
            s8v b0 = *(const s8v*)(Bls + (nt * 16 + lm) * APLD + lq * 8);
            s8v b1 = *(const s8v*)(Bls + (nt * 16 + lm) * APLD + 32 + lq * 8);
            acc[nt] = __builtin_amdgcn_mfma_f32_16x16x32_bf16(a0, b0, acc[nt], 0, 0, 0);
            acc[nt] = __builtin_amdgcn_mfma_f32_16x16x32_bf16(a1, b1, acc[nt], 0, 0, 0);
        }
        __syncthreads();
    }
    short* op = part + (size_t)s * N2 * APN;
#pragma unroll
    for (int nt = 0; nt < 17; ++nt) {
        int c = nt * 16 + lm;
#pragma unroll
        for (int i = 0; i < 4; ++i) {
            int r = row0 + w8 * 16 + lq * 4 + i;
            op[(size_t)r * APN + c] = f2b(acc[nt][i]);
        }
    }
}

// ---------------------------------------------------------------- tgp0 reduce+fixup
__global__ __launch_bounds__(256) void fix_tgp0(const short* __restrict__ part,
                                                const float* __restrict__ tgX,
                                                const float* __restrict__ rou0,
                                                const float* __restrict__ router0,
                                                short* __restrict__ outb) {
    int r = blockIdx.x;
    int tid = threadIdx.x;
    __shared__ float sAsum;
    float s0 = 0.f, s1 = 0.f;
#pragma unroll
    for (int s = 0; s < SPLITS; ++s)
        s0 += sb2f(part[((size_t)s * N2 + r) * APN + tid]);
    if (tid < 8) {
#pragma unroll
        for (int s = 0; s < SPLITS; ++s)
            s1 += sb2f(part[((size_t)s * N2 + r) * APN + 256 + tid]);
    }
    if (tid == 2) sAsum = s1;   // col 258
    __syncthreads();
    float ro = rou0[r];
    float inv = 1.f / (1.f + sAsum + ro + 1e-12f);
    {
        float v = (s0 + tgX[(size_t)r * PD + tid] + ro * router0[tid]) * inv;
        outb[(size_t)r * PD2P + tid] = f2b(v);
    }
    if (tid < 8) {
        int c = 256 + tid;
        float v = 0.f;
        if (c < PD2) v = (s1 + ro * router0[c]) * inv;
        outb[(size_t)r * PD2P + c] = f2b(v);
    }
}

// ---------------------------------------------------------------- W-layer GEMM
__global__ __launch_bounds__(256) void w_gemm(
    const short* __restrict__ A, const short* __restrict__ B,
    const float* __restrict__ bias,
    float* __restrict__ outFcol, short* __restrict__ fFbcol,
    const float* __restrict__ rou1, const float* __restrict__ router1,
    short* __restrict__ tgp1b)
{
    __shared__ __align__(16) short LDS[5120];
    short* Als = LDS;
    short* Bls = LDS + 64 * 40;
    const int tid = threadIdx.x;
    const int lane = tid & 63, wv = tid >> 6;
    const int wm = wv >> 1, wn = wv & 1;
    const int lm = lane & 15, lq = lane >> 4;
    const int row0 = blockIdx.y * 64, col0 = blockIdx.x * 64;
    const f32x4 zero4 = {0.f, 0.f, 0.f, 0.f};
    f32x4 acc[2][2] = {{zero4, zero4}, {zero4, zero4}};
    const s8v zero8 = {0, 0, 0, 0, 0, 0, 0, 0};
    const int r = tid >> 2, cgp = tid & 3;
    for (int k0 = 0; k0 < PD2P; k0 += 32) {
        int gk = k0 + cgp * 8;
        s8v va = zero8, vb = zero8;
        if (gk < PD2P) {
            va = *(const s8v*)(A + (size_t)(row0 + r) * PD2P + gk);
            if (col0 + r < PD2) vb = *(const s8v*)(B + (size_t)(col0 + r) * PD2P + gk);
        }
        *(s8v*)(Als + r * 40 + cgp * 8) = va;
        *(s8v*)(Bls + r * 40 + cgp * 8) = vb;
        __syncthreads();
        s8v af[2], bf[2];
#pragma unroll
        for (int mt = 0; mt < 2; ++mt)
            af[mt] = *(const s8v*)(Als + (wm * 32 + mt * 16 + lm) * 40 + lq * 8);
#pragma unroll
        for (int nt = 0; nt < 2; ++nt)
            bf[nt] = *(const s8v*)(Bls + (wn * 32 + nt * 16 + lm) * 40 + lq * 8);
#pragma unroll
        for (int mt = 0; mt < 2; ++mt)
#pragma unroll
            for (int nt = 0; nt < 2; ++nt)
                acc[mt][nt] = __builtin_amdgcn_mfma_f32_16x16x32_bf16(
                    af[mt], bf[nt], acc[mt][nt], 0, 0, 0);
        __syncthreads();
    }
#pragma unroll
    for (int mt = 0; mt < 2; ++mt)
#pragma unroll
        for (int nt = 0; nt < 2; ++nt) {
            int c = col0 + wn * 32 + nt * 16 + lm;
            if (c >= PD2) continue;
            float bv = bias[c];
            float rc = router1 ? router1[c] : 0.f;
#pragma unroll
            for (int i = 0; i < 4; ++i) {
                int rr = row0 + wm * 32 + mt * 16 + lq * 4 + i;
                float v = acc[mt][nt][i] + bv;
                outFcol[(size_t)rr * FD + c] = v;
                fFbcol[(size_t)rr * FDP + c] = f2b(v);
                if (tgp1b) {
                    float ro = rou1[rr];
                    tgp1b[(size_t)rr * PD2P + c] =
                        f2b((v + ro * rc) / (1.f + ro + 1e-12f));
                }
            }
        }
}

// ---------------------------------------------------------------- q2 projection (K=776)
__global__ __launch_bounds__(256) void q2_gemm(
    const short* __restrict__ A, const short* __restrict__ B,
    const float* __restrict__ bias, short* __restrict__ outB)
{
    __shared__ __align__(16) short LDS[5120];
    short* Als = LDS;
    short* Bls = LDS + 64 * 40;
    const int tid = threadIdx.x;
    const int lane = tid & 63, wv = tid >> 6;
    const int wm = wv >> 1, wn = wv & 1;
    const int lm = lane & 15, lq = lane >> 4;
    const int row0 = blockIdx.y * 64, col0 = blockIdx.x * 64;
    const f32x4 zero4 = {0.f, 0.f, 0.f, 0.f};
    f32x4 acc[2][2] = {{zero4, zero4}, {zero4, zero4}};
    const s8v zero8 = {0, 0, 0, 0, 0, 0, 0, 0};
    const int r = tid >> 2, cgp = tid & 3;
    for (int k0 = 0; k0 < FDP; k0 += 32) {
        int gk = k0 + cgp * 8;
        s8v va = zero8, vb = zero8;
        if (gk < FDP) {
            va = *(const s8v*)(A + (size_t)(row0 + r) * FDP + gk);
            vb = *(const s8v*)(B + (size_t)(col0 + r) * FDP + gk);
        }
        *(s8v*)(Als + r * 40 + cgp * 8) = va;
        *(s8v*)(Bls + r * 40 + cgp * 8) = vb;
        __syncthreads();
        s8v af[2], bf[2];
#pragma unroll
        for (int mt = 0; mt < 2; ++mt)
            af[mt] = *(const s8v*)(Als + (wm * 32 + mt * 16 + lm) * 40 + lq * 8);
#pragma unroll
        for (int nt = 0; nt < 2; ++nt)
            bf[nt] = *(const s8v*)(Bls + (wn * 32 + nt * 16 + lm) * 40 + lq * 8);
#pragma unroll
        for (int mt = 0; mt < 2; ++mt)
#pragma unroll
            for (int nt = 0; nt < 2; ++nt)
                acc[mt][nt] = __builtin_amdgcn_mfma_f32_16x16x32_bf16(
                    af[mt], bf[nt], acc[mt][nt], 0, 0, 0);
        __syncthreads();
    }
    const float INV_TEMP = 0.08838834764831845f;
#pragma unroll
    for (int mt = 0; mt < 2; ++mt)
#pragma unroll
        for (int nt = 0; nt < 2; ++nt) {
            int c = col0 + wn * 32 + nt * 16 + lm;
            float bv = bias[c];
#pragma unroll
            for (int i = 0; i < 4; ++i) {
                int rr = row0 + wm * 32 + mt * 16 + lq * 4 + i;
                outB[(size_t)rr * DZ + c] = f2b(INV_TEMP * (acc[mt][nt][i] + bv));
            }
        }
}

// ---------------------------------------------------------------- attention 2
// 512 blocks: chunk (16 x 256 cols) x rowblock (32 x 64 rows).
// Per-lane accumulation across tiles; single end-of-kernel 16-lane butterfly.
__global__ __launch_bounds__(256) void attn2_flash(
    const short* __restrict__ Q, const short* __restrict__ Kk,
    const float* __restrict__ V, float* __restrict__ part2)
{
    __shared__ __align__(16) short Qls[64 * 136];
    __shared__ __align__(16) short Kls[64 * 136];
    __shared__ float Vls[128];
    const int tid = threadIdx.x;
    const int lane = tid & 63, wv = tid >> 6;
    const int lm = lane & 15, lq = lane >> 4;
    const int chunk = blockIdx.x & 15, row0 = (blockIdx.x >> 4) * 64;
    const f32x4 zero4 = {0.f, 0.f, 0.f, 0.f};
#pragma unroll
    for (int l = 0; l < 4; ++l) {
        int id = l * 256 + tid;
        int r = id >> 4, g = id & 15;
        *(s8v*)(Qls + r * 136 + g * 8) = *(const s8v*)(Q + (size_t)(row0 + r) * DZ + g * 8);
    }
    __syncthreads();
    s8v af[4];
#pragma unroll
    for (int ks = 0; ks < 4; ++ks)
        af[ks] = *(const s8v*)(Qls + (wv * 16 + lm) * 136 + ks * 32 + lq * 8);
    float z[4] = {0.f, 0.f, 0.f, 0.f};
    float y0[4] = {0.f, 0.f, 0.f, 0.f};
    float y1[4] = {0.f, 0.f, 0.f, 0.f};
    for (int t = 0; t < 4; ++t) {
        int col0 = chunk * 256 + t * 64;
        __syncthreads();
#pragma unroll
        for (int l = 0; l < 4; ++l) {
            int id = l * 256 + tid;
            int r = id >> 4, g = id & 15;
            *(s8v*)(Kls + r * 136 + g * 8) =
                *(const s8v*)(Kk + (size_t)(col0 + r) * 256 + 128 + g * 8);
        }
        if (tid < 128) Vls[tid] = V[col0 * 2 + tid];
        __syncthreads();
        f32x4 acc[4];
#pragma unroll
        for (int nt = 0; nt < 4; ++nt) acc[nt] = zero4;
#pragma unroll
        for (int nt = 0; nt < 4; ++nt)
#pragma unroll
            for (int ks = 0; ks < 4; ++ks) {
                s8v bf = *(const s8v*)(Kls + (nt * 16 + lm) * 136 + ks * 32 + lq * 8);
                acc[nt] = __builtin_amdgcn_mfma_f32_16x16x32_bf16(af[ks], bf, acc[nt], 0, 0, 0);
            }
        float v0[4], v1[4];
#pragma unroll
        for (int nt = 0; nt < 4; ++nt) {
            v0[nt] = Vls[(nt * 16 + lm) * 2];
            v1[nt] = Vls[(nt * 16 + lm) * 2 + 1];
        }
        // per-lane accumulation: NO cross-lane ops inside the tile loop
#pragma unroll
        for (int i = 0; i < 4; ++i) {
            float e0 = __expf(acc[0][i]), e1 = __expf(acc[1][i]);
            float e2 = __expf(acc[2][i]), e3 = __expf(acc[3][i]);
            z[i]  += e0 + e1 + e2 + e3;
            y0[i] += e0 * v0[0] + e1 * v0[1] + e2 * v0[2] + e3 * v0[3];
            y1[i] += e0 * v1[0] + e1 * v1[1] + e2 * v1[2] + e3 * v1[3];
        }
    }
    // single end-of-kernel butterfly over the 16 column-lanes
#pragma unroll
    for (int i = 0; i < 4; ++i) {
#pragma unroll
        for (int msk = 1; msk < 16; msk <<= 1) {
            z[i]  += __shfl_xor(z[i], msk, 64);
            y0[i] += __shfl_xor(y0[i], msk, 64);
            y1[i] += __shfl_xor(y1[i], msk, 64);
        }
    }
    if (lm == 0) {
#pragma unroll
        for (int i = 0; i < 4; ++i) {
            int r = row0 + wv * 16 + lq * 4 + i;
            float* pp = part2 + ((size_t)r * 16 + chunk) * 4;
            pp[0] = z[i]; pp[1] = y0[i]; pp[2] = y1[i];
        }
    }
}

__global__ void attn2_combine(const float* __restrict__ part2, float* __restrict__ out) {
    int r = blockIdx.x * 256 + threadIdx.x;
    if (r >= N2) return;
    const float* pp = part2 + (size_t)r * 64;
    float Zt = 0.f, Y0 = 0.f, Y1 = 0.f;
#pragma unroll
    for (int c = 0; c < 16; ++c) {
        Zt += pp[c * 4]; Y0 += pp[c * 4 + 1]; Y1 += pp[c * 4 + 2];
    }
    out[2 * r] = Y0 / Zt;
    out[2 * r + 1] = Y1 / Zt;
}

// ---------------------------------------------------------------- launch
extern "C" void kernel_launch(void* const* d_in, const int* in_sizes, int n_in,
                              void* d_out, int out_size, void* d_ws, size_t ws_size,
                              hipStream_t stream) {
    const float* lm_X = (const float*)d_in[0];
    const float* lm_Y = (const float*)d_in[1];
    const float* tg_X = (const float*)d_in[2];
    const float* lm_delay = (const float*)d_in[4];
    const float* tg_delay = (const float*)d_in[5];
    const float* aq_w = (const float*)d_in[6];
    const float* aq_b = (const float*)d_in[7];
    const float* ak_w = (const float*)d_in[8];
    const float* ak_b = (const float*)d_in[9];
    const float* w1_w = (const float*)d_in[10];
    const float* w1_b = (const float*)d_in[11];
    const float* w2_w = (const float*)d_in[12];
    const float* w2_b = (const float*)d_in[13];
    const float* pq_w = (const float*)d_in[14];
    const float* pq_b = (const float*)d_in[15];
    const float* pk_w = (const float*)d_in[16];
    const float* pk_b = (const float*)d_in[17];
    const float* pv_w = (const float*)d_in[18];
    const float* pv_b = (const float*)d_in[19];
    const float* g1 = (const float*)d_in[20];
    const float* g2 = (const float*)d_in[21];
    const float* g3 = (const float*)d_in[22];
    const float* al = (const float*)d_in[23];
    const float* be = (const float*)d_in[24];

    float* out = (float*)d_out;
    float* outF = out + (size_t)N2 * 2;

    char* base = (char*)d_ws;
    size_t off = 0;
    auto allocF = [&](size_t n) -> float* {
        float* q = (float*)(base + off);
        off += (n * 4 + 255) / 256 * 256;
        return q;
    };
    auto allocS = [&](size_t n) -> short* {
        short* q = (short*)(base + off);
        off += (n * 2 + 255) / 256 * 256;
        return q;
    };

    short* E        = allocS((size_t)N2 * N1);
    short* appart   = allocS((size_t)SPLITS * N2 * APN);
    short* lmFTb    = allocS((size_t)APN * N1);
    short* qb       = allocS((size_t)N2 * DZ);
    short* kk       = allocS((size_t)N1 * 256);
    short* q2       = allocS((size_t)N2 * DZ);
    short* tgp0b    = allocS((size_t)N2 * PD2P);
    short* tgp1b    = allocS((size_t)N2 * PD2P);
    short* finalFb  = allocS((size_t)N2 * FDP);
    short* w1wb     = allocS((size_t)PD2 * PD2P);
    short* w2wb     = allocS((size_t)PD2 * PD2P);
    short* pqwb     = allocS((size_t)DZ * FDP);
    float* v2b      = allocF((size_t)N1 * 2);
    float* part2    = allocF((size_t)N2 * 64);
    float* Zbuf     = allocF(N2);
    float* router0  = allocF(PD2);
    float* routerp0 = allocF(PD2);
    float* router1  = allocF(PD2);
    float* dscore   = allocF(N1);
    float* rou0     = allocF(N2);
    float* rou1     = allocF(N2);

    // 1. conversions / copies / zero-fills
    hipLaunchKernelGGL(cvt_all, dim3((R8 + 255) / 256), dim3(256), 0, stream,
                       lm_X, lm_Y, tg_X, pq_w, w1_w, w2_w,
                       lm_delay, tg_delay, g1, g2, g3, al, be, pv_w, pv_b,
                       w1wb, w2wb, pqwb, lmFTb,
                       dscore, rou0, rou1, v2b, Zbuf, finalFb, tgp1b, outF);
    // 2. router + kk + qb (one kernel, 578 blocks)
    hipLaunchKernelGGL(rkq_kernel, dim3(578), dim3(256), 0, stream,
                       lm_X, tg_X, aq_w, aq_b, ak_w, ak_b, pk_w, pk_b,
                       lmFTb, dscore, router0, routerp0, kk, qb);
    // 3. E = exp(scores), Z rowsums (+router1 block)
    hipLaunchKernelGGL(scores_e, dim3(513), dim3(256), 0, stream,
                       qb, kk, E, Zbuf, routerp0, w1_w, w1_b, router1);
    // 4. AP partials (bf16)
    hipLaunchKernelGGL(ap_gemm, dim3(256), dim3(512), 0, stream, E, Zbuf, lmFTb, appart);
    // 5. tgp0
    hipLaunchKernelGGL(fix_tgp0, dim3(N2), dim3(256), 0, stream,
                       appart, tg_X, rou0, router0, tgp0b);
    // 6. tf1 (+ fused tgp1)
    hipLaunchKernelGGL(w_gemm, dim3(5, 32), dim3(256), 0, stream,
                       tgp0b, w1wb, w1_b, outF + 256, finalFb + 256, rou1, router1, tgp1b);
    // 7. tf2
    hipLaunchKernelGGL(w_gemm, dim3(5, 32), dim3(256), 0, stream,
                       tgp1b, w2wb, w2_b, outF + 514, finalFb + 514,
                       nullptr, nullptr, nullptr);
    // 8. q2
    hipLaunchKernelGGL(q2_gemm, dim3(2, 32), dim3(256), 0, stream,
                       finalFb, pqwb, pq_b, q2);
    // 9-10. attention 2 + combine
    hipLaunchKernelGGL(attn2_flash, dim3(512), dim3(256), 0, stream,
                       q2, kk, v2b, part2);
    hipLaunchKernelGGL(attn2_combine, dim3(8), dim3(256), 0, stream, part2, out);
}